// Round 1
// baseline (386.090 us; speedup 1.0000x reference)
//
#include <hip/hip_runtime.h>
#include <cstdint>
#include <cstddef>

typedef unsigned long long u64;
typedef unsigned int u32;

#define NN 2048
#define DD 512
#define EE 65536
#define NW 32   // 64-bit words per bitset row (2048/64)

// ---------- helpers ----------
__device__ __forceinline__ u32 fmap(float x) {
    u32 u = __float_as_uint(x);
    return (u & 0x80000000u) ? ~u : (u | 0x80000000u);
}
__device__ __forceinline__ float funmap(u32 u) {
    return (u & 0x80000000u) ? __uint_as_float(u ^ 0x80000000u) : __uint_as_float(~u);
}

// ---------- init small arrays ----------
__global__ void k_init(u32* mmax, float* ssum, u64* centerBits, u64* colAny) {
    int t = blockIdx.x * blockDim.x + threadIdx.x;
    if (t < NN) { mmax[t] = 0u; ssum[t] = 0.0f; }
    if (t < NW) { centerBits[t] = 0ull; colAny[t] = 0ull; }
}

// ---------- per-node: inv_norm, a = emb.W1, c = emb.W2 ----------
__global__ __launch_bounds__(256) void k_node(const float* __restrict__ emb,
                                              const float* __restrict__ Wsc,
                                              float* inv_norm, float* av, float* cv) {
    int n = blockIdx.x;
    int t = threadIdx.x;
    const float* row = emb + (size_t)n * DD;
    float ss = 0.f, aa = 0.f, cc = 0.f;
    for (int d = t; d < DD; d += 256) {
        float v = row[d];
        ss += v * v;
        aa += v * Wsc[d];
        cc += v * Wsc[DD + d];
    }
    for (int off = 32; off; off >>= 1) {
        ss += __shfl_down(ss, off);
        aa += __shfl_down(aa, off);
        cc += __shfl_down(cc, off);
    }
    __shared__ float red[3][4];
    int wid = t >> 6, lane = t & 63;
    if (lane == 0) { red[0][wid] = ss; red[1][wid] = aa; red[2][wid] = cc; }
    __syncthreads();
    if (t == 0) {
        float s = 0.f, a = 0.f, c = 0.f;
        for (int w = 0; w < 4; w++) { s += red[0][w]; a += red[1][w]; c += red[2][w]; }
        inv_norm[n] = 1.0f / fmaxf(sqrtf(s), 1e-12f);
        av[n] = a;
        cv[n] = c;
    }
}

// ---------- edge passes ----------
__device__ __forceinline__ float edge_score(const int* ei, const float* av, const float* cv,
                                            float b0, int e, int* src, int* dst) {
    int s = ei[e], d = ei[EE + e];
    *src = s; *dst = d;
    float x = av[s] + cv[d] + b0;
    return x > 0.f ? x : 0.01f * x;   // leaky_relu
}

__global__ void k_edge_max(const int* __restrict__ ei, const float* __restrict__ av,
                           const float* __restrict__ cv, const float* __restrict__ bsc,
                           u32* mmax) {
    int e = blockIdx.x * 256 + threadIdx.x;
    if (e >= EE) return;
    int s, d;
    float x = edge_score(ei, av, cv, bsc[0], e, &s, &d);
    atomicMax(&mmax[s], fmap(x));
}

__global__ void k_edge_sum(const int* __restrict__ ei, const float* __restrict__ av,
                           const float* __restrict__ cv, const float* __restrict__ bsc,
                           const u32* __restrict__ mmax, float* ssum) {
    int e = blockIdx.x * 256 + threadIdx.x;
    if (e >= EE) return;
    int s, d;
    float x = edge_score(ei, av, cv, bsc[0], e, &s, &d);
    float w = expf(x - funmap(mmax[s]));
    atomicAdd(&ssum[s], w);
}

// adds softmax weight into fitness (must run AFTER k_fitness wrote fitness)
__global__ void k_edge_scatter(const int* __restrict__ ei, const float* __restrict__ av,
                               const float* __restrict__ cv, const float* __restrict__ bsc,
                               const u32* __restrict__ mmax, const float* __restrict__ ssum,
                               float* fit) {
    int e = blockIdx.x * 256 + threadIdx.x;
    if (e >= EE) return;
    int s, d;
    float x = edge_score(ei, av, cv, bsc[0], e, &s, &d);
    float w = expf(x - funmap(mmax[s])) / (ssum[s] + 1e-16f);
    atomicAdd(&fit[(size_t)s * NN + d], w);
}

// ---------- fitness = (Z Z^T): tiled fp32, 64x64 tile, 4x4 per thread ----------
__global__ __launch_bounds__(256) void k_fitness(const float* __restrict__ emb,
                                                 const float* __restrict__ inv,
                                                 float* __restrict__ fit) {
    __shared__ float As[64][20];
    __shared__ float Bs[64][20];
    int tx = threadIdx.x & 15, ty = threadIdx.x >> 4;
    int rowBase = blockIdx.y * 64, colBase = blockIdx.x * 64;
    float acc[4][4] = {};
    int lr = threadIdx.x >> 2;         // 0..63
    int lc = (threadIdx.x & 3) * 4;    // 0,4,8,12
    for (int k0 = 0; k0 < DD; k0 += 16) {
        float4 va = *reinterpret_cast<const float4*>(emb + (size_t)(rowBase + lr) * DD + k0 + lc);
        float4 vb = *reinterpret_cast<const float4*>(emb + (size_t)(colBase + lr) * DD + k0 + lc);
        *reinterpret_cast<float4*>(&As[lr][lc]) = va;
        *reinterpret_cast<float4*>(&Bs[lr][lc]) = vb;
        __syncthreads();
#pragma unroll
        for (int kk = 0; kk < 16; kk++) {
            float a[4], b[4];
#pragma unroll
            for (int u = 0; u < 4; u++) a[u] = As[ty + 16 * u][kk];
#pragma unroll
            for (int v = 0; v < 4; v++) b[v] = Bs[tx + 16 * v][kk];
#pragma unroll
            for (int u = 0; u < 4; u++)
#pragma unroll
                for (int v = 0; v < 4; v++) acc[u][v] += a[u] * b[v];
        }
        __syncthreads();
    }
#pragma unroll
    for (int u = 0; u < 4; u++) {
        int i = rowBase + ty + 16 * u;
        float iv = inv[i];
#pragma unroll
        for (int v = 0; v < 4; v++) {
            int j = colBase + tx + 16 * v;
            fit[(size_t)i * NN + j] = acc[u][v] * iv * inv[j];
        }
    }
}

// ---------- A1 bitset: edge && !diag && fitness>=0 ----------
__global__ void k_bits(const float* __restrict__ edge_m, const float* __restrict__ fit,
                       u64* __restrict__ A1w) {
    int i = blockIdx.x;
    int t = threadIdx.x;
    int lane = t & 63, wv = t >> 6;
    for (int q = 0; q < 8; q++) {
        int j = q * 256 + t;
        float em = edge_m[(size_t)i * NN + j];
        float f = fit[(size_t)i * NN + j];
        bool pred = (em != 0.f) && (j != i) && (f >= 0.f);
        u64 word = __ballot(pred);
        if (lane == 0) A1w[i * NW + q * 4 + wv] = word;
    }
}

// ---------- boolean A1@A1 via bitset row-OR; A2, cluster, colAny ----------
__global__ __launch_bounds__(256) void k_paths2(const u64* __restrict__ A1w,
                                                u64* __restrict__ A2w, u64* __restrict__ CLw,
                                                u64* colAny) {
    int i = blockIdx.x;
    __shared__ u64 rowA[NW];
    __shared__ u64 part[8][NW];
    int t = threadIdx.x;
    if (t < NW) rowA[t] = A1w[i * NW + t];
    __syncthreads();
    int g = t >> 5, w = t & 31;
    u64 acc = 0;
    for (int ww = 0; ww < 4; ww++) {
        u64 bits = rowA[g * 4 + ww];
        int kbase = (g * 4 + ww) * 64;
        while (bits) {
            int k = __ffsll((unsigned long long)bits) - 1;
            bits &= bits - 1;
            acc |= A1w[(size_t)(kbase + k) * NW + w];
        }
    }
    part[g][w] = acc;
    __syncthreads();
    if (g == 0) {
        u64 p2 = part[0][w];
#pragma unroll
        for (int gg = 1; gg < 8; gg++) p2 |= part[gg][w];
        if ((i >> 6) == w) p2 &= ~(1ull << (i & 63));   // zero diagonal of A1@A1
        u64 a1 = rowA[w];
        u64 a2 = p2 & ~a1;          // (A1@A1>0.5) minus A1, clamped
        u64 cl = a1 | a2;           // (A1+A2) > 0
        A2w[i * NW + w] = a2;
        CLw[i * NW + w] = cl;
        atomicOr(&colAny[w], cl);   // column-presence OR (for isolated)
    }
}

// ---------- cluster scores ----------
__global__ __launch_bounds__(256) void k_scores(const float* __restrict__ fit,
                                                const u64* __restrict__ A1w,
                                                const u64* __restrict__ A2w,
                                                float* cs) {
    int i = blockIdx.x, t = threadIdx.x;
    float s1 = 0.f, s2 = 0.f;
    int d1 = 0, d2 = 0;
    for (int q = 0; q < 8; q++) {
        int j = q * 256 + t;
        float f = fit[(size_t)i * NN + j];
        int w = j >> 6, b = j & 63;
        u64 a1 = A1w[i * NW + w], a2 = A2w[i * NW + w];
        if ((a1 >> b) & 1) { s1 += f; d1++; }
        if ((a2 >> b) & 1) { s2 += f; d2++; }
    }
    for (int off = 32; off; off >>= 1) {
        s1 += __shfl_down(s1, off);
        s2 += __shfl_down(s2, off);
        d1 += __shfl_down(d1, off);
        d2 += __shfl_down(d2, off);
    }
    __shared__ float rs1[4], rs2[4];
    __shared__ int rd1[4], rd2[4];
    int wid = t >> 6, lane = t & 63;
    if (lane == 0) { rs1[wid] = s1; rs2[wid] = s2; rd1[wid] = d1; rd2[wid] = d2; }
    __syncthreads();
    if (t == 0) {
        float S1 = 0.f, S2 = 0.f; int D1 = 0, D2 = 0;
        for (int w = 0; w < 4; w++) { S1 += rs1[w]; S2 += rs2[w]; D1 += rd1[w]; D2 += rd2[w]; }
        float v1 = D1 > 0 ? S1 / (float)D1 : 0.f;
        float v2 = D2 > 0 ? S2 / (float)D2 : 0.f;
        cs[i] = 0.5f * (v1 + v2);
    }
}

// ---------- local extrema ----------
__global__ __launch_bounds__(256) void k_extrema(const u64* __restrict__ A1w,
                                                 const float* __restrict__ cs,
                                                 unsigned char* is_c, u64* centerBits) {
    int i = blockIdx.x, t = threadIdx.x;
    float ci = cs[i];
    int ok = 1;
    for (int q = 0; q < 8; q++) {
        int j = q * 256 + t;
        u64 a1 = A1w[i * NW + (j >> 6)];
        float other = ((a1 >> (j & 63)) & 1) ? cs[j] : 0.0f;
        ok &= ((ci - other) > 0.0f) ? 1 : 0;
    }
    int all = __syncthreads_and(ok);
    if (t == 0) {
        is_c[i] = (unsigned char)(all ? 1 : 0);
        if (all) atomicOr(&centerBits[i >> 6], 1ull << (i & 63));
    }
}

// ---------- reduced = has-center-neighbor | isolated ----------
__global__ void k_reduced(const u64* __restrict__ CLw, const u64* __restrict__ centerBits,
                          const u64* __restrict__ colAny, unsigned char* reduced) {
    __shared__ u64 cb[NW];
    if (threadIdx.x < NW) cb[threadIdx.x] = centerBits[threadIdx.x];
    __syncthreads();
    int i = blockIdx.x * 256 + threadIdx.x;
    if (i >= NN) return;
    bool red = false;
    for (int w = 0; w < NW; w++) red |= (CLw[(size_t)i * NW + w] & cb[w]) != 0ull;
    bool iso = ((colAny[i >> 6] >> (i & 63)) & 1ull) == 0ull;
    reduced[i] = (unsigned char)((red || iso) ? 1 : 0);
}

// ---------- build M in-place over fitness ----------
__global__ void k_build_M(float* __restrict__ fit, const u64* __restrict__ CLw,
                          const unsigned char* __restrict__ is_c,
                          const unsigned char* __restrict__ reduced) {
    int i = blockIdx.x, t = threadIdx.x;
    for (int q = 0; q < 8; q++) {
        int j = q * 256 + t;
        bool center_ok = is_c[j] && !reduced[j];
        u64 cl = CLw[i * NW + (j >> 6)];
        bool on = center_ok && ((cl >> (j & 63)) & 1);
        size_t idx = (size_t)i * NN + j;
        float f = fit[idx];
        fit[idx] = on ? f : 0.0f;
    }
}

// ---------- pooled = M^T @ emb + (!reduced) * diag(emb) ----------
__global__ __launch_bounds__(256) void k_pooled(const float* __restrict__ M,
                                                const float* __restrict__ emb,
                                                const unsigned char* __restrict__ reduced,
                                                float* __restrict__ out) {
    __shared__ float Ms[16][68];
    __shared__ float Es[16][68];
    int tx = threadIdx.x & 15, ty = threadIdx.x >> 4;
    int jBase = blockIdx.y * 64, dBase = blockIdx.x * 64;
    float acc[4][4] = {};
    int lk = threadIdx.x >> 4;          // 0..15 (k row of tile)
    int lc = (threadIdx.x & 15) * 4;    // 0..60 (col in tile)
    for (int i0 = 0; i0 < NN; i0 += 16) {
        *reinterpret_cast<float4*>(&Ms[lk][lc]) =
            *reinterpret_cast<const float4*>(M + (size_t)(i0 + lk) * NN + jBase + lc);
        *reinterpret_cast<float4*>(&Es[lk][lc]) =
            *reinterpret_cast<const float4*>(emb + (size_t)(i0 + lk) * DD + dBase + lc);
        __syncthreads();
#pragma unroll
        for (int kk = 0; kk < 16; kk++) {
            float a[4], b[4];
#pragma unroll
            for (int u = 0; u < 4; u++) a[u] = Ms[kk][ty + 16 * u];
#pragma unroll
            for (int v = 0; v < 4; v++) b[v] = Es[kk][tx + 16 * v];
#pragma unroll
            for (int u = 0; u < 4; u++)
#pragma unroll
                for (int v = 0; v < 4; v++) acc[u][v] += a[u] * b[v];
        }
        __syncthreads();
    }
#pragma unroll
    for (int u = 0; u < 4; u++) {
        int j = jBase + ty + 16 * u;
        float dg = reduced[j] ? 0.0f : 1.0f;
#pragma unroll
        for (int v = 0; v < 4; v++) {
            int d = dBase + tx + 16 * v;
            out[(size_t)j * DD + d] = acc[u][v] + dg * emb[(size_t)j * DD + d];
        }
    }
}

// ---------- launch ----------
extern "C" void kernel_launch(void* const* d_in, const int* in_sizes, int n_in,
                              void* d_out, int out_size, void* d_ws, size_t ws_size,
                              hipStream_t stream) {
    const float* emb    = (const float*)d_in[0];
    const int*   ei     = (const int*)d_in[1];
    const float* edge_m = (const float*)d_in[2];
    // d_in[3] = edge_matrix_weight (identical to edge_matrix, unused by reference math)
    const float* Wsc    = (const float*)d_in[4];
    const float* bsc    = (const float*)d_in[5];
    float* out = (float*)d_out;

    char* ws = (char*)d_ws;
    size_t off = 0;
    auto alloc = [&](size_t bytes) -> char* {
        char* p = ws + off;
        off = (off + bytes + 255) & ~(size_t)255;
        return p;
    };
    float* fit       = (float*)alloc((size_t)NN * NN * 4);   // 16 MB (becomes M in-place)
    u64*   A1w       = (u64*)alloc((size_t)NN * NW * 8);
    u64*   A2w       = (u64*)alloc((size_t)NN * NW * 8);
    u64*   CLw       = (u64*)alloc((size_t)NN * NW * 8);
    u64*   centerBits= (u64*)alloc(NW * 8);
    u64*   colAny    = (u64*)alloc(NW * 8);
    float* inv_norm  = (float*)alloc(NN * 4);
    float* av        = (float*)alloc(NN * 4);
    float* cv        = (float*)alloc(NN * 4);
    float* ssum      = (float*)alloc(NN * 4);
    float* cs        = (float*)alloc(NN * 4);
    u32*   mmax      = (u32*)alloc(NN * 4);
    unsigned char* is_c    = (unsigned char*)alloc(NN);
    unsigned char* reduced = (unsigned char*)alloc(NN);

    k_init<<<dim3((NN + 255) / 256), dim3(256), 0, stream>>>(mmax, ssum, centerBits, colAny);
    k_node<<<dim3(NN), dim3(256), 0, stream>>>(emb, Wsc, inv_norm, av, cv);
    k_edge_max<<<dim3(EE / 256), dim3(256), 0, stream>>>(ei, av, cv, bsc, mmax);
    k_edge_sum<<<dim3(EE / 256), dim3(256), 0, stream>>>(ei, av, cv, bsc, mmax, ssum);
    k_fitness<<<dim3(NN / 64, NN / 64), dim3(256), 0, stream>>>(emb, inv_norm, fit);
    k_edge_scatter<<<dim3(EE / 256), dim3(256), 0, stream>>>(ei, av, cv, bsc, mmax, ssum, fit);
    k_bits<<<dim3(NN), dim3(256), 0, stream>>>(edge_m, fit, A1w);
    k_paths2<<<dim3(NN), dim3(256), 0, stream>>>(A1w, A2w, CLw, colAny);
    k_scores<<<dim3(NN), dim3(256), 0, stream>>>(fit, A1w, A2w, cs);
    k_extrema<<<dim3(NN), dim3(256), 0, stream>>>(A1w, cs, is_c, centerBits);
    k_reduced<<<dim3((NN + 255) / 256), dim3(256), 0, stream>>>(CLw, centerBits, colAny, reduced);
    k_build_M<<<dim3(NN), dim3(256), 0, stream>>>(fit, CLw, is_c, reduced);
    k_pooled<<<dim3(DD / 64, NN / 64), dim3(256), 0, stream>>>(fit, emb, reduced, out);
}

// Round 2
// 245.922 us; speedup vs baseline: 1.5700x; 1.5700x over previous
//
#include <hip/hip_runtime.h>
#include <cstdint>
#include <cstddef>

typedef unsigned long long u64;
typedef unsigned int u32;

#define NN 2048
#define DD 512
#define EE 65536
#define NW 32   // 64-bit words per bitset row (2048/64)

// ---------- helpers ----------
__device__ __forceinline__ u32 fmap(float x) {
    u32 u = __float_as_uint(x);
    return (u & 0x80000000u) ? ~u : (u | 0x80000000u);
}
__device__ __forceinline__ float funmap(u32 u) {
    return (u & 0x80000000u) ? __uint_as_float(u ^ 0x80000000u) : __uint_as_float(~u);
}

// ---------- init: zero small arrays + edge bitset ----------
__global__ void k_init(u32* mmax, float* ssum, u64* centerBits, u64* colAny, u64* EBw) {
    int t = blockIdx.x * blockDim.x + threadIdx.x;   // 0..65535
    EBw[t] = 0ull;                                   // NN*NW = 65536 words
    if (t < NN) { mmax[t] = 0u; ssum[t] = 0.0f; }
    if (t < NW) { centerBits[t] = 0ull; colAny[t] = 0ull; }
}

// ---------- edge bitset from edge_index (replaces reading dense edge_matrix) ----------
__global__ void k_edge_bits(const int* __restrict__ ei, u64* EBw) {
    int e = blockIdx.x * 256 + threadIdx.x;
    if (e >= EE) return;
    int s = ei[e], d = ei[EE + e];
    atomicOr(&EBw[(size_t)s * NW + (d >> 6)], 1ull << (d & 63));
}

// ---------- per-node: inv_norm, a = emb.W1, c = emb.W2 ----------
__global__ __launch_bounds__(256) void k_node(const float* __restrict__ emb,
                                              const float* __restrict__ Wsc,
                                              float* inv_norm, float* av, float* cv) {
    int n = blockIdx.x;
    int t = threadIdx.x;
    const float* row = emb + (size_t)n * DD;
    float ss = 0.f, aa = 0.f, cc = 0.f;
    for (int d = t; d < DD; d += 256) {
        float v = row[d];
        ss += v * v;
        aa += v * Wsc[d];
        cc += v * Wsc[DD + d];
    }
    for (int off = 32; off; off >>= 1) {
        ss += __shfl_down(ss, off);
        aa += __shfl_down(aa, off);
        cc += __shfl_down(cc, off);
    }
    __shared__ float red[3][4];
    int wid = t >> 6, lane = t & 63;
    if (lane == 0) { red[0][wid] = ss; red[1][wid] = aa; red[2][wid] = cc; }
    __syncthreads();
    if (t == 0) {
        float s = 0.f, a = 0.f, c = 0.f;
        for (int w = 0; w < 4; w++) { s += red[0][w]; a += red[1][w]; c += red[2][w]; }
        inv_norm[n] = 1.0f / fmaxf(sqrtf(s), 1e-12f);
        av[n] = a;
        cv[n] = c;
    }
}

// ---------- edge passes ----------
__device__ __forceinline__ float edge_score(const int* ei, const float* av, const float* cv,
                                            float b0, int e, int* src, int* dst) {
    int s = ei[e], d = ei[EE + e];
    *src = s; *dst = d;
    float x = av[s] + cv[d] + b0;
    return x > 0.f ? x : 0.01f * x;   // leaky_relu
}

__global__ void k_edge_max(const int* __restrict__ ei, const float* __restrict__ av,
                           const float* __restrict__ cv, const float* __restrict__ bsc,
                           u32* mmax) {
    int e = blockIdx.x * 256 + threadIdx.x;
    if (e >= EE) return;
    int s, d;
    float x = edge_score(ei, av, cv, bsc[0], e, &s, &d);
    atomicMax(&mmax[s], fmap(x));
}

__global__ void k_edge_sum(const int* __restrict__ ei, const float* __restrict__ av,
                           const float* __restrict__ cv, const float* __restrict__ bsc,
                           const u32* __restrict__ mmax, float* ssum) {
    int e = blockIdx.x * 256 + threadIdx.x;
    if (e >= EE) return;
    int s, d;
    float x = edge_score(ei, av, cv, bsc[0], e, &s, &d);
    float w = expf(x - funmap(mmax[s]));
    atomicAdd(&ssum[s], w);
}

// adds softmax weight into fitness (runs AFTER k_fitness wrote fitness)
__global__ void k_edge_scatter(const int* __restrict__ ei, const float* __restrict__ av,
                               const float* __restrict__ cv, const float* __restrict__ bsc,
                               const u32* __restrict__ mmax, const float* __restrict__ ssum,
                               float* fit) {
    int e = blockIdx.x * 256 + threadIdx.x;
    if (e >= EE) return;
    int s, d;
    float x = edge_score(ei, av, cv, bsc[0], e, &s, &d);
    float w = expf(x - funmap(mmax[s])) / (ssum[s] + 1e-16f);
    atomicAdd(&fit[(size_t)s * NN + d], w);
}

// ---------- fitness = Z Z^T : 128x128 tile, 512 thr, 8x4 micro, k-major LDS ----------
#define BKF 16
__global__ __launch_bounds__(512) void k_fitness(const float* __restrict__ emb,
                                                 const float* __restrict__ inv,
                                                 float* __restrict__ fit) {
    __shared__ float As[BKF][132];
    __shared__ float Bs[BKF][132];
    int tid = threadIdx.x;
    int tx = tid & 31;        // col group (*4)
    int ty = tid >> 5;        // row group (*8), 0..15
    int rowBase = blockIdx.y * 128, colBase = blockIdx.x * 128;
    float acc[8][4] = {};
    int sr = tid >> 2;              // stage row 0..127
    int sc = (tid & 3) * 4;         // stage k offset 0,4,8,12
    const float* pa = emb + (size_t)(rowBase + sr) * DD + sc;
    const float* pb = emb + (size_t)(colBase + sr) * DD + sc;
    for (int k0 = 0; k0 < DD; k0 += BKF) {
        float4 va = *reinterpret_cast<const float4*>(pa + k0);
        float4 vb = *reinterpret_cast<const float4*>(pb + k0);
        __syncthreads();
        As[sc + 0][sr] = va.x; As[sc + 1][sr] = va.y; As[sc + 2][sr] = va.z; As[sc + 3][sr] = va.w;
        Bs[sc + 0][sr] = vb.x; Bs[sc + 1][sr] = vb.y; Bs[sc + 2][sr] = vb.z; Bs[sc + 3][sr] = vb.w;
        __syncthreads();
#pragma unroll
        for (int kk = 0; kk < BKF; kk++) {
            float a[8], b[4];
            *reinterpret_cast<float4*>(&a[0]) = *reinterpret_cast<const float4*>(&As[kk][ty * 8]);
            *reinterpret_cast<float4*>(&a[4]) = *reinterpret_cast<const float4*>(&As[kk][ty * 8 + 4]);
            *reinterpret_cast<float4*>(&b[0]) = *reinterpret_cast<const float4*>(&Bs[kk][tx * 4]);
#pragma unroll
            for (int u = 0; u < 8; u++)
#pragma unroll
                for (int v = 0; v < 4; v++) acc[u][v] += a[u] * b[v];
        }
    }
    float4 ivj = *reinterpret_cast<const float4*>(inv + colBase + tx * 4);
#pragma unroll
    for (int u = 0; u < 8; u++) {
        int i = rowBase + ty * 8 + u;
        float iv = inv[i];
        float4 o;
        o.x = acc[u][0] * iv * ivj.x;
        o.y = acc[u][1] * iv * ivj.y;
        o.z = acc[u][2] * iv * ivj.z;
        o.w = acc[u][3] * iv * ivj.w;
        *reinterpret_cast<float4*>(fit + (size_t)i * NN + colBase + tx * 4) = o;
    }
}

// ---------- A1 bitset: edge && !diag && fitness>=0 ----------
__global__ void k_bits(const u64* __restrict__ EBw, const float* __restrict__ fit,
                       u64* __restrict__ A1w) {
    int i = blockIdx.x;
    int t = threadIdx.x;
    int lane = t & 63, wv = t >> 6;
    for (int q = 0; q < 8; q++) {
        int j = q * 256 + t;
        u64 eb = EBw[(size_t)i * NW + (j >> 6)];
        float f = fit[(size_t)i * NN + j];
        bool pred = ((eb >> (j & 63)) & 1) && (j != i) && (f >= 0.f);
        u64 word = __ballot(pred);
        if (lane == 0) A1w[i * NW + q * 4 + wv] = word;
    }
}

// ---------- boolean A1@A1 via bitset row-OR; A2, cluster, colAny ----------
__global__ __launch_bounds__(256) void k_paths2(const u64* __restrict__ A1w,
                                                u64* __restrict__ A2w, u64* __restrict__ CLw,
                                                u64* colAny) {
    int i = blockIdx.x;
    __shared__ u64 rowA[NW];
    __shared__ u64 part[8][NW];
    int t = threadIdx.x;
    if (t < NW) rowA[t] = A1w[i * NW + t];
    __syncthreads();
    int g = t >> 5, w = t & 31;
    u64 acc = 0;
    for (int ww = 0; ww < 4; ww++) {
        u64 bits = rowA[g * 4 + ww];
        int kbase = (g * 4 + ww) * 64;
        while (bits) {
            int k = __ffsll((unsigned long long)bits) - 1;
            bits &= bits - 1;
            acc |= A1w[(size_t)(kbase + k) * NW + w];
        }
    }
    part[g][w] = acc;
    __syncthreads();
    if (g == 0) {
        u64 p2 = part[0][w];
#pragma unroll
        for (int gg = 1; gg < 8; gg++) p2 |= part[gg][w];
        if ((i >> 6) == w) p2 &= ~(1ull << (i & 63));   // zero diagonal of A1@A1
        u64 a1 = rowA[w];
        u64 a2 = p2 & ~a1;          // (A1@A1>0.5) minus A1, clamped
        u64 cl = a1 | a2;           // (A1+A2) > 0
        A2w[i * NW + w] = a2;
        CLw[i * NW + w] = cl;
        atomicOr(&colAny[w], cl);   // column-presence OR (for isolated)
    }
}

// ---------- cluster scores ----------
__global__ __launch_bounds__(256) void k_scores(const float* __restrict__ fit,
                                                const u64* __restrict__ A1w,
                                                const u64* __restrict__ A2w,
                                                float* cs) {
    int i = blockIdx.x, t = threadIdx.x;
    float s1 = 0.f, s2 = 0.f;
    int d1 = 0, d2 = 0;
    for (int q = 0; q < 8; q++) {
        int j = q * 256 + t;
        float f = fit[(size_t)i * NN + j];
        int w = j >> 6, b = j & 63;
        u64 a1 = A1w[i * NW + w], a2 = A2w[i * NW + w];
        if ((a1 >> b) & 1) { s1 += f; d1++; }
        if ((a2 >> b) & 1) { s2 += f; d2++; }
    }
    for (int off = 32; off; off >>= 1) {
        s1 += __shfl_down(s1, off);
        s2 += __shfl_down(s2, off);
        d1 += __shfl_down(d1, off);
        d2 += __shfl_down(d2, off);
    }
    __shared__ float rs1[4], rs2[4];
    __shared__ int rd1[4], rd2[4];
    int wid = t >> 6, lane = t & 63;
    if (lane == 0) { rs1[wid] = s1; rs2[wid] = s2; rd1[wid] = d1; rd2[wid] = d2; }
    __syncthreads();
    if (t == 0) {
        float S1 = 0.f, S2 = 0.f; int D1 = 0, D2 = 0;
        for (int w = 0; w < 4; w++) { S1 += rs1[w]; S2 += rs2[w]; D1 += rd1[w]; D2 += rd2[w]; }
        float v1 = D1 > 0 ? S1 / (float)D1 : 0.f;
        float v2 = D2 > 0 ? S2 / (float)D2 : 0.f;
        cs[i] = 0.5f * (v1 + v2);
    }
}

// ---------- local extrema ----------
__global__ __launch_bounds__(256) void k_extrema(const u64* __restrict__ A1w,
                                                 const float* __restrict__ cs,
                                                 unsigned char* is_c, u64* centerBits) {
    int i = blockIdx.x, t = threadIdx.x;
    float ci = cs[i];
    int ok = 1;
    for (int q = 0; q < 8; q++) {
        int j = q * 256 + t;
        u64 a1 = A1w[i * NW + (j >> 6)];
        float other = ((a1 >> (j & 63)) & 1) ? cs[j] : 0.0f;
        ok &= ((ci - other) > 0.0f) ? 1 : 0;
    }
    int all = __syncthreads_and(ok);
    if (t == 0) {
        is_c[i] = (unsigned char)(all ? 1 : 0);
        if (all) atomicOr(&centerBits[i >> 6], 1ull << (i & 63));
    }
}

// ---------- reduced = has-center-neighbor | isolated ----------
__global__ void k_reduced(const u64* __restrict__ CLw, const u64* __restrict__ centerBits,
                          const u64* __restrict__ colAny, unsigned char* reduced) {
    __shared__ u64 cb[NW];
    if (threadIdx.x < NW) cb[threadIdx.x] = centerBits[threadIdx.x];
    __syncthreads();
    int i = blockIdx.x * 256 + threadIdx.x;
    if (i >= NN) return;
    bool red = false;
    for (int w = 0; w < NW; w++) red |= (CLw[(size_t)i * NW + w] & cb[w]) != 0ull;
    bool iso = ((colAny[i >> 6] >> (i & 63)) & 1ull) == 0ull;
    reduced[i] = (unsigned char)((red || iso) ? 1 : 0);
}

// ---------- pooled: sparse-column M^T @ emb ----------
// out[j] = (!reduced[j])*emb[j] + [center_ok(j)] * sum_i cluster[i][j]*fit[i][j]*emb[i]
__global__ __launch_bounds__(256) void k_pooled(const float* __restrict__ fit,
                                                const float* __restrict__ emb,
                                                const u64* __restrict__ CLw,
                                                const unsigned char* __restrict__ is_c,
                                                const unsigned char* __restrict__ reduced,
                                                float* __restrict__ out) {
    int j = blockIdx.x;
    int t = threadIdx.x;
    bool red = reduced[j];
    const float2* embj = reinterpret_cast<const float2*>(emb + (size_t)j * DD);
    float2* outj = reinterpret_cast<float2*>(out + (size_t)j * DD);
    bool active = is_c[j] && !red;
    if (!active) {
        float dg = red ? 0.0f : 1.0f;
        float2 v = embj[t];
        float2 o; o.x = v.x * dg; o.y = v.y * dg;
        outj[t] = o;
        return;
    }
    // deterministic ordered compaction of column j's (i, weight) pairs
    __shared__ int lidx[NN];
    __shared__ float lwt[NN];
    __shared__ int wcnt[4];
    int wid = t >> 6, lane = t & 63;
    int wsh = j >> 6;
    u64 bmask = 1ull << (j & 63);
    int total = 0;
    for (int q = 0; q < 8; q++) {
        int i = q * 256 + t;
        u64 cw = CLw[(size_t)i * NW + wsh];
        bool p = (cw & bmask) != 0ull;
        float f = 0.f;
        if (p) f = fit[(size_t)i * NN + j];
        u64 mask = __ballot(p);
        if (lane == 0) wcnt[wid] = __popcll(mask);
        __syncthreads();
        int off = total;
        for (int w = 0; w < wid; w++) off += wcnt[w];
        int tq = wcnt[0] + wcnt[1] + wcnt[2] + wcnt[3];
        if (p) {
            int pos = off + __popcll(mask & ((1ull << lane) - 1ull));
            lidx[pos] = i;
            lwt[pos] = f;
        }
        total += tq;
        __syncthreads();
    }
    float2 acc = {0.f, 0.f};
#pragma unroll 4
    for (int k = 0; k < total; k++) {
        int i = lidx[k];
        float w = lwt[k];
        float2 e = reinterpret_cast<const float2*>(emb + (size_t)i * DD)[t];
        acc.x += w * e.x;
        acc.y += w * e.y;
    }
    float2 v = embj[t];      // diag term, dg = 1 on active path
    acc.x += v.x;
    acc.y += v.y;
    outj[t] = acc;
}

// ---------- launch ----------
extern "C" void kernel_launch(void* const* d_in, const int* in_sizes, int n_in,
                              void* d_out, int out_size, void* d_ws, size_t ws_size,
                              hipStream_t stream) {
    const float* emb = (const float*)d_in[0];
    const int*   ei  = (const int*)d_in[1];
    // d_in[2] = edge_matrix  (reconstructed from edge_index as a bitset instead)
    // d_in[3] = edge_matrix_weight (unused by reference math)
    const float* Wsc = (const float*)d_in[4];
    const float* bsc = (const float*)d_in[5];
    float* out = (float*)d_out;

    char* ws = (char*)d_ws;
    size_t off = 0;
    auto alloc = [&](size_t bytes) -> char* {
        char* p = ws + off;
        off = (off + bytes + 255) & ~(size_t)255;
        return p;
    };
    float* fit        = (float*)alloc((size_t)NN * NN * 4);   // 16 MB
    u64*   A1w        = (u64*)alloc((size_t)NN * NW * 8);
    u64*   A2w        = (u64*)alloc((size_t)NN * NW * 8);
    u64*   CLw        = (u64*)alloc((size_t)NN * NW * 8);
    u64*   EBw        = (u64*)alloc((size_t)NN * NW * 8);
    u64*   centerBits = (u64*)alloc(NW * 8);
    u64*   colAny     = (u64*)alloc(NW * 8);
    float* inv_norm   = (float*)alloc(NN * 4);
    float* av         = (float*)alloc(NN * 4);
    float* cv         = (float*)alloc(NN * 4);
    float* ssum       = (float*)alloc(NN * 4);
    float* cs         = (float*)alloc(NN * 4);
    u32*   mmax       = (u32*)alloc(NN * 4);
    unsigned char* is_c    = (unsigned char*)alloc(NN);
    unsigned char* reduced = (unsigned char*)alloc(NN);

    k_init<<<dim3(NN * NW / 256), dim3(256), 0, stream>>>(mmax, ssum, centerBits, colAny, EBw);
    k_node<<<dim3(NN), dim3(256), 0, stream>>>(emb, Wsc, inv_norm, av, cv);
    k_edge_bits<<<dim3(EE / 256), dim3(256), 0, stream>>>(ei, EBw);
    k_edge_max<<<dim3(EE / 256), dim3(256), 0, stream>>>(ei, av, cv, bsc, mmax);
    k_edge_sum<<<dim3(EE / 256), dim3(256), 0, stream>>>(ei, av, cv, bsc, mmax, ssum);
    k_fitness<<<dim3(NN / 128, NN / 128), dim3(512), 0, stream>>>(emb, inv_norm, fit);
    k_edge_scatter<<<dim3(EE / 256), dim3(256), 0, stream>>>(ei, av, cv, bsc, mmax, ssum, fit);
    k_bits<<<dim3(NN), dim3(256), 0, stream>>>(EBw, fit, A1w);
    k_paths2<<<dim3(NN), dim3(256), 0, stream>>>(A1w, A2w, CLw, colAny);
    k_scores<<<dim3(NN), dim3(256), 0, stream>>>(fit, A1w, A2w, cs);
    k_extrema<<<dim3(NN), dim3(256), 0, stream>>>(A1w, cs, is_c, centerBits);
    k_reduced<<<dim3(NN / 256), dim3(256), 0, stream>>>(CLw, centerBits, colAny, reduced);
    k_pooled<<<dim3(NN), dim3(256), 0, stream>>>(fit, emb, CLw, is_c, reduced, out);
}

// Round 3
// 205.978 us; speedup vs baseline: 1.8744x; 1.1939x over previous
//
#include <hip/hip_runtime.h>
#include <cstdint>
#include <cstddef>

typedef unsigned long long u64;
typedef unsigned int u32;
typedef _Float16 half8 __attribute__((ext_vector_type(8)));
typedef float f32x4 __attribute__((ext_vector_type(4)));

#define NN 2048
#define DD 512
#define EE 65536
#define NW 32   // 64-bit words per bitset row (2048/64)

// ---------- helpers ----------
__device__ __forceinline__ u32 fmap(float x) {
    u32 u = __float_as_uint(x);
    return (u & 0x80000000u) ? ~u : (u | 0x80000000u);
}
__device__ __forceinline__ float funmap(u32 u) {
    return (u & 0x80000000u) ? __uint_as_float(u ^ 0x80000000u) : __uint_as_float(~u);
}

// ---------- init: zero small arrays + edge bitset ----------
__global__ void k_init(u32* mmax, float* ssum, u64* centerBits, u64* colAny, u64* EBw) {
    int t = blockIdx.x * blockDim.x + threadIdx.x;   // 0..65535
    EBw[t] = 0ull;                                   // NN*NW = 65536 words
    if (t < NN) { mmax[t] = 0u; ssum[t] = 0.0f; }
    if (t < NW) { centerBits[t] = 0ull; colAny[t] = 0ull; }
}

// ---------- edge bitset from edge_index ----------
__global__ void k_edge_bits(const int* __restrict__ ei, u64* EBw) {
    int e = blockIdx.x * 256 + threadIdx.x;
    if (e >= EE) return;
    int s = ei[e], d = ei[EE + e];
    atomicOr(&EBw[(size_t)s * NW + (d >> 6)], 1ull << (d & 63));
}

// ---------- per-node: inv_norm, a = emb.W1, c = emb.W2 ----------
__global__ __launch_bounds__(256) void k_node(const float* __restrict__ emb,
                                              const float* __restrict__ Wsc,
                                              float* inv_norm, float* av, float* cv) {
    int n = blockIdx.x;
    int t = threadIdx.x;
    const float* row = emb + (size_t)n * DD;
    float ss = 0.f, aa = 0.f, cc = 0.f;
    for (int d = t; d < DD; d += 256) {
        float v = row[d];
        ss += v * v;
        aa += v * Wsc[d];
        cc += v * Wsc[DD + d];
    }
    for (int off = 32; off; off >>= 1) {
        ss += __shfl_down(ss, off);
        aa += __shfl_down(aa, off);
        cc += __shfl_down(cc, off);
    }
    __shared__ float red[3][4];
    int wid = t >> 6, lane = t & 63;
    if (lane == 0) { red[0][wid] = ss; red[1][wid] = aa; red[2][wid] = cc; }
    __syncthreads();
    if (t == 0) {
        float s = 0.f, a = 0.f, c = 0.f;
        for (int w = 0; w < 4; w++) { s += red[0][w]; a += red[1][w]; c += red[2][w]; }
        inv_norm[n] = 1.0f / fmaxf(sqrtf(s), 1e-12f);
        av[n] = a;
        cv[n] = c;
    }
}

// ---------- split z = emb*inv into f16 hi + f16 lo ----------
__global__ __launch_bounds__(256) void k_split(const float* __restrict__ emb,
                                               const float* __restrict__ inv,
                                               _Float16* __restrict__ zh,
                                               _Float16* __restrict__ zl) {
    int i = blockIdx.x;
    float iv = inv[i];
    for (int d = threadIdx.x; d < DD; d += 256) {
        float z = emb[(size_t)i * DD + d] * iv;
        _Float16 h = (_Float16)z;
        _Float16 l = (_Float16)(z - (float)h);
        zh[(size_t)i * DD + d] = h;
        zl[(size_t)i * DD + d] = l;
    }
}

// ---------- edge passes ----------
__device__ __forceinline__ float edge_score(const int* ei, const float* av, const float* cv,
                                            float b0, int e, int* src, int* dst) {
    int s = ei[e], d = ei[EE + e];
    *src = s; *dst = d;
    float x = av[s] + cv[d] + b0;
    return x > 0.f ? x : 0.01f * x;   // leaky_relu
}

__global__ void k_edge_max(const int* __restrict__ ei, const float* __restrict__ av,
                           const float* __restrict__ cv, const float* __restrict__ bsc,
                           u32* mmax) {
    int e = blockIdx.x * 256 + threadIdx.x;
    if (e >= EE) return;
    int s, d;
    float x = edge_score(ei, av, cv, bsc[0], e, &s, &d);
    atomicMax(&mmax[s], fmap(x));
}

__global__ void k_edge_sum(const int* __restrict__ ei, const float* __restrict__ av,
                           const float* __restrict__ cv, const float* __restrict__ bsc,
                           const u32* __restrict__ mmax, float* ssum) {
    int e = blockIdx.x * 256 + threadIdx.x;
    if (e >= EE) return;
    int s, d;
    float x = edge_score(ei, av, cv, bsc[0], e, &s, &d);
    float w = expf(x - funmap(mmax[s]));
    atomicAdd(&ssum[s], w);
}

__global__ void k_edge_scatter(const int* __restrict__ ei, const float* __restrict__ av,
                               const float* __restrict__ cv, const float* __restrict__ bsc,
                               const u32* __restrict__ mmax, const float* __restrict__ ssum,
                               float* fit) {
    int e = blockIdx.x * 256 + threadIdx.x;
    if (e >= EE) return;
    int s, d;
    float x = edge_score(ei, av, cv, bsc[0], e, &s, &d);
    float w = expf(x - funmap(mmax[s])) / (ssum[s] + 1e-16f);
    atomicAdd(&fit[(size_t)s * NN + d], w);
}

// ---------- fitness = Z Z^T via f16-split triple MFMA ----------
// C = Zh Zh^T + Zh Zl^T + Zl Zh^T  (lo*lo dropped, ~1e-8 cos error)
// 128x128 tile, 4 waves, wave = 4x4 frags of 16x16x32. BK=64, 64KB LDS.
// XOR swizzle: 16B slot' = slot ^ (row&7)  (applied at stage-src and frag-read).
#define BK 64
__global__ __launch_bounds__(256) void k_fitness(const _Float16* __restrict__ zh,
                                                 const _Float16* __restrict__ zl,
                                                 float* __restrict__ fit) {
    __shared__ _Float16 Ah[128 * BK];
    __shared__ _Float16 Al[128 * BK];
    __shared__ _Float16 Bh[128 * BK];
    __shared__ _Float16 Bl[128 * BK];
    int tid = threadIdx.x;
    int wid = tid >> 6, lane = tid & 63;
    int wr = wid >> 1, wc = wid & 1;          // wave 2x2 grid of 64x64 sub-tiles
    int I = blockIdx.y * 128, J = blockIdx.x * 128;
    int lr = lane & 15;                        // frag row/col
    int q = lane >> 4;                         // k-group 0..3
    f32x4 acc[4][4] = {};
    for (int k0 = 0; k0 < DD; k0 += BK) {
        __syncthreads();
        // stage: 4 chunks/thread/array; LDS linear dest, XOR-swizzled global src
#pragma unroll
        for (int s = 0; s < 4; s++) {
            int id = (s << 8) + tid;
            int rl = id >> 3, sl = id & 7;
            int ks = ((sl ^ (rl & 7)) << 3);                 // element offset in row
            size_t gA = (size_t)(I + rl) * DD + k0 + ks;
            size_t gB = (size_t)(J + rl) * DD + k0 + ks;
            int lo = rl * BK + sl * 8;
            *reinterpret_cast<half8*>(&Ah[lo]) = *reinterpret_cast<const half8*>(&zh[gA]);
            *reinterpret_cast<half8*>(&Al[lo]) = *reinterpret_cast<const half8*>(&zl[gA]);
            *reinterpret_cast<half8*>(&Bh[lo]) = *reinterpret_cast<const half8*>(&zh[gB]);
            *reinterpret_cast<half8*>(&Bl[lo]) = *reinterpret_cast<const half8*>(&zl[gB]);
        }
        __syncthreads();
#pragma unroll
        for (int kk = 0; kk < 2; kk++) {
            half8 a_h[4], a_l[4], b_h[4], b_l[4];
#pragma unroll
            for (int f = 0; f < 4; f++) {
                int ra = wr * 64 + f * 16 + lr;
                int ca = (kk * 4 + q) ^ (ra & 7);
                int oa = ra * BK + ca * 8;
                a_h[f] = *reinterpret_cast<const half8*>(&Ah[oa]);
                a_l[f] = *reinterpret_cast<const half8*>(&Al[oa]);
                int rb = wc * 64 + f * 16 + lr;
                int cb = (kk * 4 + q) ^ (rb & 7);
                int ob = rb * BK + cb * 8;
                b_h[f] = *reinterpret_cast<const half8*>(&Bh[ob]);
                b_l[f] = *reinterpret_cast<const half8*>(&Bl[ob]);
            }
#pragma unroll
            for (int u = 0; u < 4; u++)
#pragma unroll
                for (int v = 0; v < 4; v++) {
                    acc[u][v] = __builtin_amdgcn_mfma_f32_16x16x32_f16(a_h[u], b_h[v], acc[u][v], 0, 0, 0);
                    acc[u][v] = __builtin_amdgcn_mfma_f32_16x16x32_f16(a_h[u], b_l[v], acc[u][v], 0, 0, 0);
                    acc[u][v] = __builtin_amdgcn_mfma_f32_16x16x32_f16(a_l[u], b_h[v], acc[u][v], 0, 0, 0);
                }
        }
    }
    // epilogue: C/D layout col=lane&15, row=(lane>>4)*4+reg  (m89-verified)
#pragma unroll
    for (int u = 0; u < 4; u++) {
        int r = I + wr * 64 + u * 16 + q * 4;
#pragma unroll
        for (int v = 0; v < 4; v++) {
            int c = J + wc * 64 + v * 16 + lr;
#pragma unroll
            for (int i2 = 0; i2 < 4; i2++)
                fit[(size_t)(r + i2) * NN + c] = acc[u][v][i2];
        }
    }
}

// ---------- A1 bitset: edge && !diag && fitness>=0 ----------
__global__ void k_bits(const u64* __restrict__ EBw, const float* __restrict__ fit,
                       u64* __restrict__ A1w) {
    int i = blockIdx.x;
    int t = threadIdx.x;
    int lane = t & 63, wv = t >> 6;
    for (int q = 0; q < 8; q++) {
        int j = q * 256 + t;
        u64 eb = EBw[(size_t)i * NW + (j >> 6)];
        float f = fit[(size_t)i * NN + j];
        bool pred = ((eb >> (j & 63)) & 1) && (j != i) && (f >= 0.f);
        u64 word = __ballot(pred);
        if (lane == 0) A1w[i * NW + q * 4 + wv] = word;
    }
}

// ---------- boolean A1@A1 via bitset row-OR; A2, cluster, colAny ----------
__global__ __launch_bounds__(256) void k_paths2(const u64* __restrict__ A1w,
                                                u64* __restrict__ A2w, u64* __restrict__ CLw,
                                                u64* colAny) {
    int i = blockIdx.x;
    __shared__ u64 rowA[NW];
    __shared__ u64 part[8][NW];
    int t = threadIdx.x;
    if (t < NW) rowA[t] = A1w[i * NW + t];
    __syncthreads();
    int g = t >> 5, w = t & 31;
    u64 acc = 0;
    for (int ww = 0; ww < 4; ww++) {
        u64 bits = rowA[g * 4 + ww];
        int kbase = (g * 4 + ww) * 64;
        while (bits) {
            int k = __ffsll((unsigned long long)bits) - 1;
            bits &= bits - 1;
            acc |= A1w[(size_t)(kbase + k) * NW + w];
        }
    }
    part[g][w] = acc;
    __syncthreads();
    if (g == 0) {
        u64 p2 = part[0][w];
#pragma unroll
        for (int gg = 1; gg < 8; gg++) p2 |= part[gg][w];
        if ((i >> 6) == w) p2 &= ~(1ull << (i & 63));   // zero diagonal of A1@A1
        u64 a1 = rowA[w];
        u64 a2 = p2 & ~a1;          // (A1@A1>0.5) minus A1, clamped
        u64 cl = a1 | a2;           // (A1+A2) > 0
        A2w[i * NW + w] = a2;
        CLw[i * NW + w] = cl;
        atomicOr(&colAny[w], cl);   // column-presence OR (for isolated)
    }
}

// ---------- cluster scores ----------
__global__ __launch_bounds__(256) void k_scores(const float* __restrict__ fit,
                                                const u64* __restrict__ A1w,
                                                const u64* __restrict__ A2w,
                                                float* cs) {
    int i = blockIdx.x, t = threadIdx.x;
    float s1 = 0.f, s2 = 0.f;
    int d1 = 0, d2 = 0;
    for (int q = 0; q < 8; q++) {
        int j = q * 256 + t;
        float f = fit[(size_t)i * NN + j];
        int w = j >> 6, b = j & 63;
        u64 a1 = A1w[i * NW + w], a2 = A2w[i * NW + w];
        if ((a1 >> b) & 1) { s1 += f; d1++; }
        if ((a2 >> b) & 1) { s2 += f; d2++; }
    }
    for (int off = 32; off; off >>= 1) {
        s1 += __shfl_down(s1, off);
        s2 += __shfl_down(s2, off);
        d1 += __shfl_down(d1, off);
        d2 += __shfl_down(d2, off);
    }
    __shared__ float rs1[4], rs2[4];
    __shared__ int rd1[4], rd2[4];
    int wid = t >> 6, lane = t & 63;
    if (lane == 0) { rs1[wid] = s1; rs2[wid] = s2; rd1[wid] = d1; rd2[wid] = d2; }
    __syncthreads();
    if (t == 0) {
        float S1 = 0.f, S2 = 0.f; int D1 = 0, D2 = 0;
        for (int w = 0; w < 4; w++) { S1 += rs1[w]; S2 += rs2[w]; D1 += rd1[w]; D2 += rd2[w]; }
        float v1 = D1 > 0 ? S1 / (float)D1 : 0.f;
        float v2 = D2 > 0 ? S2 / (float)D2 : 0.f;
        cs[i] = 0.5f * (v1 + v2);
    }
}

// ---------- local extrema ----------
__global__ __launch_bounds__(256) void k_extrema(const u64* __restrict__ A1w,
                                                 const float* __restrict__ cs,
                                                 unsigned char* is_c, u64* centerBits) {
    int i = blockIdx.x, t = threadIdx.x;
    float ci = cs[i];
    int ok = 1;
    for (int q = 0; q < 8; q++) {
        int j = q * 256 + t;
        u64 a1 = A1w[i * NW + (j >> 6)];
        float other = ((a1 >> (j & 63)) & 1) ? cs[j] : 0.0f;
        ok &= ((ci - other) > 0.0f) ? 1 : 0;
    }
    int all = __syncthreads_and(ok);
    if (t == 0) {
        is_c[i] = (unsigned char)(all ? 1 : 0);
        if (all) atomicOr(&centerBits[i >> 6], 1ull << (i & 63));
    }
}

// ---------- pooled: sparse-column M^T @ emb, reduced computed inline ----------
__global__ __launch_bounds__(256) void k_pooled(const float* __restrict__ fit,
                                                const float* __restrict__ emb,
                                                const u64* __restrict__ CLw,
                                                const u64* __restrict__ centerBits,
                                                const u64* __restrict__ colAny,
                                                const unsigned char* __restrict__ is_c,
                                                float* __restrict__ out) {
    int j = blockIdx.x;
    int t = threadIdx.x;
    // reduced[j] = (cluster-row j contains a center) | (column j empty)
    bool red = ((colAny[j >> 6] >> (j & 63)) & 1ull) == 0ull;
    for (int w = 0; w < NW; w++) red |= (CLw[(size_t)j * NW + w] & centerBits[w]) != 0ull;
    const float2* embj = reinterpret_cast<const float2*>(emb + (size_t)j * DD);
    float2* outj = reinterpret_cast<float2*>(out + (size_t)j * DD);
    bool active = is_c[j] && !red;
    if (!active) {
        float dg = red ? 0.0f : 1.0f;
        float2 v = embj[t];
        float2 o; o.x = v.x * dg; o.y = v.y * dg;
        outj[t] = o;
        return;
    }
    // deterministic ordered compaction of column j's (i, weight) pairs
    __shared__ int lidx[NN];
    __shared__ float lwt[NN];
    __shared__ int wcnt[4];
    int wid = t >> 6, lane = t & 63;
    int wsh = j >> 6;
    u64 bmask = 1ull << (j & 63);
    int total = 0;
    for (int qq = 0; qq < 8; qq++) {
        int i = qq * 256 + t;
        u64 cw = CLw[(size_t)i * NW + wsh];
        bool p = (cw & bmask) != 0ull;
        float f = 0.f;
        if (p) f = fit[(size_t)i * NN + j];
        u64 mask = __ballot(p);
        if (lane == 0) wcnt[wid] = __popcll(mask);
        __syncthreads();
        int off = total;
        for (int w = 0; w < wid; w++) off += wcnt[w];
        int tq = wcnt[0] + wcnt[1] + wcnt[2] + wcnt[3];
        if (p) {
            int pos = off + __popcll(mask & ((1ull << lane) - 1ull));
            lidx[pos] = i;
            lwt[pos] = f;
        }
        total += tq;
        __syncthreads();
    }
    float2 acc = {0.f, 0.f};
#pragma unroll 4
    for (int k = 0; k < total; k++) {
        int i = lidx[k];
        float w = lwt[k];
        float2 e = reinterpret_cast<const float2*>(emb + (size_t)i * DD)[t];
        acc.x += w * e.x;
        acc.y += w * e.y;
    }
    float2 v = embj[t];      // diag term (dg=1 on active path)
    acc.x += v.x;
    acc.y += v.y;
    outj[t] = acc;
}

// ---------- launch ----------
extern "C" void kernel_launch(void* const* d_in, const int* in_sizes, int n_in,
                              void* d_out, int out_size, void* d_ws, size_t ws_size,
                              hipStream_t stream) {
    const float* emb = (const float*)d_in[0];
    const int*   ei  = (const int*)d_in[1];
    // d_in[2] = edge_matrix  (reconstructed from edge_index as a bitset)
    // d_in[3] = edge_matrix_weight (unused by reference math)
    const float* Wsc = (const float*)d_in[4];
    const float* bsc = (const float*)d_in[5];
    float* out = (float*)d_out;

    char* ws = (char*)d_ws;
    size_t off = 0;
    auto alloc = [&](size_t bytes) -> char* {
        char* p = ws + off;
        off = (off + bytes + 255) & ~(size_t)255;
        return p;
    };
    float* fit  = (float*)alloc((size_t)NN * NN * 4);      // 16 MB
    // zh/zl (4 MB) die after k_fitness; A1w/A2w/CLw (1.5 MB) are born after -> alias
    char*  zblk = alloc((size_t)2 * NN * DD * 2);          // 4 MB shared region
    _Float16* zh = (_Float16*)zblk;
    _Float16* zl = (_Float16*)(zblk + (size_t)NN * DD * 2);
    u64* A1w = (u64*)zblk;
    u64* A2w = (u64*)(zblk + (size_t)NN * NW * 8);
    u64* CLw = (u64*)(zblk + (size_t)2 * NN * NW * 8);
    u64*   EBw        = (u64*)alloc((size_t)NN * NW * 8);  // live across fitness
    u64*   centerBits = (u64*)alloc(NW * 8);
    u64*   colAny     = (u64*)alloc(NW * 8);
    float* inv_norm   = (float*)alloc(NN * 4);
    float* av         = (float*)alloc(NN * 4);
    float* cv         = (float*)alloc(NN * 4);
    float* ssum       = (float*)alloc(NN * 4);
    float* cs         = (float*)alloc(NN * 4);
    u32*   mmax       = (u32*)alloc(NN * 4);
    unsigned char* is_c = (unsigned char*)alloc(NN);

    k_init<<<dim3(NN * NW / 256), dim3(256), 0, stream>>>(mmax, ssum, centerBits, colAny, EBw);
    k_node<<<dim3(NN), dim3(256), 0, stream>>>(emb, Wsc, inv_norm, av, cv);
    k_edge_bits<<<dim3(EE / 256), dim3(256), 0, stream>>>(ei, EBw);
    k_edge_max<<<dim3(EE / 256), dim3(256), 0, stream>>>(ei, av, cv, bsc, mmax);
    k_edge_sum<<<dim3(EE / 256), dim3(256), 0, stream>>>(ei, av, cv, bsc, mmax, ssum);
    k_split<<<dim3(NN), dim3(256), 0, stream>>>(emb, inv_norm, zh, zl);
    k_fitness<<<dim3(NN / 128, NN / 128), dim3(256), 0, stream>>>(zh, zl, fit);
    k_edge_scatter<<<dim3(EE / 256), dim3(256), 0, stream>>>(ei, av, cv, bsc, mmax, ssum, fit);
    k_bits<<<dim3(NN), dim3(256), 0, stream>>>(EBw, fit, A1w);
    k_paths2<<<dim3(NN), dim3(256), 0, stream>>>(A1w, A2w, CLw, colAny);
    k_scores<<<dim3(NN), dim3(256), 0, stream>>>(fit, A1w, A2w, cs);
    k_extrema<<<dim3(NN), dim3(256), 0, stream>>>(A1w, cs, is_c, centerBits);
    k_pooled<<<dim3(NN), dim3(256), 0, stream>>>(fit, emb, CLw, centerBits, colAny, is_c, out);
}

// Round 4
// 195.178 us; speedup vs baseline: 1.9781x; 1.0553x over previous
//
#include <hip/hip_runtime.h>
#include <cstdint>
#include <cstddef>

typedef unsigned long long u64;
typedef unsigned int u32;
typedef _Float16 half8 __attribute__((ext_vector_type(8)));
typedef float f32x4 __attribute__((ext_vector_type(4)));

#define NN 2048
#define DD 512
#define EE 65536
#define NW 32   // 64-bit words per bitset row (2048/64)

// ---------- helpers ----------
__device__ __forceinline__ u32 fmap(float x) {
    u32 u = __float_as_uint(x);
    return (u & 0x80000000u) ? ~u : (u | 0x80000000u);
}
__device__ __forceinline__ float funmap(u32 u) {
    return (u & 0x80000000u) ? __uint_as_float(u ^ 0x80000000u) : __uint_as_float(~u);
}

// ---------- fused: init scratch + per-node reductions + f16 split ----------
// grid 2048 blocks x 256 thr. Blocks 0..255 zero EBw, 256..263 zero mmax/ssum,
// 264 zeroes centerBits/colAny (init is independent of the node work).
__global__ __launch_bounds__(256) void k_node(const float* __restrict__ emb,
                                              const float* __restrict__ Wsc,
                                              float* inv_norm, float* av, float* cv,
                                              _Float16* __restrict__ zh,
                                              _Float16* __restrict__ zl,
                                              u32* mmax, float* ssum,
                                              u64* centerBits, u64* colAny, u64* EBw) {
    int n = blockIdx.x;
    int t = threadIdx.x;
    if (n < 256) EBw[n * 256 + t] = 0ull;
    else if (n < 264) { int idx = (n - 256) * 256 + t; mmax[idx] = 0u; ssum[idx] = 0.0f; }
    else if (n == 264 && t < NW) { centerBits[t] = 0ull; colAny[t] = 0ull; }

    const float* row = emb + (size_t)n * DD;
    float ss = 0.f, aa = 0.f, cc = 0.f;
    for (int d = t; d < DD; d += 256) {
        float v = row[d];
        ss += v * v;
        aa += v * Wsc[d];
        cc += v * Wsc[DD + d];
    }
    for (int off = 32; off; off >>= 1) {
        ss += __shfl_down(ss, off);
        aa += __shfl_down(aa, off);
        cc += __shfl_down(cc, off);
    }
    __shared__ float red[3][4];
    __shared__ float s_inv;
    int wid = t >> 6, lane = t & 63;
    if (lane == 0) { red[0][wid] = ss; red[1][wid] = aa; red[2][wid] = cc; }
    __syncthreads();
    if (t == 0) {
        float s = 0.f, a = 0.f, c = 0.f;
        for (int w = 0; w < 4; w++) { s += red[0][w]; a += red[1][w]; c += red[2][w]; }
        float iv = 1.0f / fmaxf(sqrtf(s), 1e-12f);
        inv_norm[n] = iv;
        s_inv = iv;
        av[n] = a;
        cv[n] = c;
    }
    __syncthreads();
    float iv = s_inv;
    for (int d = t; d < DD; d += 256) {
        float z = row[d] * iv;
        _Float16 h = (_Float16)z;
        _Float16 l = (_Float16)(z - (float)h);
        zh[(size_t)n * DD + d] = h;
        zl[(size_t)n * DD + d] = l;
    }
}

// ---------- edge passes ----------
__device__ __forceinline__ float edge_score(const int* ei, const float* av, const float* cv,
                                            float b0, int e, int* src, int* dst) {
    int s = ei[e], d = ei[EE + e];
    *src = s; *dst = d;
    float x = av[s] + cv[d] + b0;
    return x > 0.f ? x : 0.01f * x;   // leaky_relu
}

// fused: edge bitset + segment max
__global__ __launch_bounds__(256) void k_edgeA(const int* __restrict__ ei,
                                               const float* __restrict__ av,
                                               const float* __restrict__ cv,
                                               const float* __restrict__ bsc,
                                               u32* mmax, u64* EBw) {
    int e = blockIdx.x * 256 + threadIdx.x;
    if (e >= EE) return;
    int s, d;
    float x = edge_score(ei, av, cv, bsc[0], e, &s, &d);
    atomicMax(&mmax[s], fmap(x));
    atomicOr(&EBw[(size_t)s * NW + (d >> 6)], 1ull << (d & 63));
}

__global__ __launch_bounds__(256) void k_edge_sum(const int* __restrict__ ei,
                                                  const float* __restrict__ av,
                                                  const float* __restrict__ cv,
                                                  const float* __restrict__ bsc,
                                                  const u32* __restrict__ mmax, float* ssum) {
    int e = blockIdx.x * 256 + threadIdx.x;
    if (e >= EE) return;
    int s, d;
    float x = edge_score(ei, av, cv, bsc[0], e, &s, &d);
    float w = expf(x - funmap(mmax[s]));
    atomicAdd(&ssum[s], w);
}

__global__ __launch_bounds__(256) void k_edge_scatter(const int* __restrict__ ei,
                                                      const float* __restrict__ av,
                                                      const float* __restrict__ cv,
                                                      const float* __restrict__ bsc,
                                                      const u32* __restrict__ mmax,
                                                      const float* __restrict__ ssum,
                                                      float* fit) {
    int e = blockIdx.x * 256 + threadIdx.x;
    if (e >= EE) return;
    int s, d;
    float x = edge_score(ei, av, cv, bsc[0], e, &s, &d);
    float w = expf(x - funmap(mmax[s])) / (ssum[s] + 1e-16f);
    atomicAdd(&fit[(size_t)s * NN + d], w);
}

// ---------- fitness = Z Z^T via f16-split triple MFMA ----------
#define BK 64
__global__ __launch_bounds__(256) void k_fitness(const _Float16* __restrict__ zh,
                                                 const _Float16* __restrict__ zl,
                                                 float* __restrict__ fit) {
    __shared__ _Float16 Ah[128 * BK];
    __shared__ _Float16 Al[128 * BK];
    __shared__ _Float16 Bh[128 * BK];
    __shared__ _Float16 Bl[128 * BK];
    int tid = threadIdx.x;
    int wid = tid >> 6, lane = tid & 63;
    int wr = wid >> 1, wc = wid & 1;          // wave 2x2 grid of 64x64 sub-tiles
    int I = blockIdx.y * 128, J = blockIdx.x * 128;
    int lr = lane & 15;                        // frag row/col
    int q = lane >> 4;                         // k-group 0..3
    f32x4 acc[4][4] = {};
    for (int k0 = 0; k0 < DD; k0 += BK) {
        __syncthreads();
#pragma unroll
        for (int s = 0; s < 4; s++) {
            int id = (s << 8) + tid;
            int rl = id >> 3, sl = id & 7;
            int ks = ((sl ^ (rl & 7)) << 3);
            size_t gA = (size_t)(I + rl) * DD + k0 + ks;
            size_t gB = (size_t)(J + rl) * DD + k0 + ks;
            int lo = rl * BK + sl * 8;
            *reinterpret_cast<half8*>(&Ah[lo]) = *reinterpret_cast<const half8*>(&zh[gA]);
            *reinterpret_cast<half8*>(&Al[lo]) = *reinterpret_cast<const half8*>(&zl[gA]);
            *reinterpret_cast<half8*>(&Bh[lo]) = *reinterpret_cast<const half8*>(&zh[gB]);
            *reinterpret_cast<half8*>(&Bl[lo]) = *reinterpret_cast<const half8*>(&zl[gB]);
        }
        __syncthreads();
#pragma unroll
        for (int kk = 0; kk < 2; kk++) {
            half8 a_h[4], a_l[4], b_h[4], b_l[4];
#pragma unroll
            for (int f = 0; f < 4; f++) {
                int ra = wr * 64 + f * 16 + lr;
                int ca = (kk * 4 + q) ^ (ra & 7);
                int oa = ra * BK + ca * 8;
                a_h[f] = *reinterpret_cast<const half8*>(&Ah[oa]);
                a_l[f] = *reinterpret_cast<const half8*>(&Al[oa]);
                int rb = wc * 64 + f * 16 + lr;
                int cb = (kk * 4 + q) ^ (rb & 7);
                int ob = rb * BK + cb * 8;
                b_h[f] = *reinterpret_cast<const half8*>(&Bh[ob]);
                b_l[f] = *reinterpret_cast<const half8*>(&Bl[ob]);
            }
#pragma unroll
            for (int u = 0; u < 4; u++)
#pragma unroll
                for (int v = 0; v < 4; v++) {
                    acc[u][v] = __builtin_amdgcn_mfma_f32_16x16x32_f16(a_h[u], b_h[v], acc[u][v], 0, 0, 0);
                    acc[u][v] = __builtin_amdgcn_mfma_f32_16x16x32_f16(a_h[u], b_l[v], acc[u][v], 0, 0, 0);
                    acc[u][v] = __builtin_amdgcn_mfma_f32_16x16x32_f16(a_l[u], b_h[v], acc[u][v], 0, 0, 0);
                }
        }
    }
#pragma unroll
    for (int u = 0; u < 4; u++) {
        int r = I + wr * 64 + u * 16 + q * 4;
#pragma unroll
        for (int v = 0; v < 4; v++) {
            int c = J + wc * 64 + v * 16 + lr;
#pragma unroll
            for (int i2 = 0; i2 < 4; i2++)
                fit[(size_t)(r + i2) * NN + c] = acc[u][v][i2];
        }
    }
}

// ---------- A1 bitset: edge && !diag && fitness>=0 ----------
__global__ void k_bits(const u64* __restrict__ EBw, const float* __restrict__ fit,
                       u64* __restrict__ A1w) {
    int i = blockIdx.x;
    int t = threadIdx.x;
    int lane = t & 63, wv = t >> 6;
    for (int q = 0; q < 8; q++) {
        int j = q * 256 + t;
        u64 eb = EBw[(size_t)i * NW + (j >> 6)];
        float f = fit[(size_t)i * NN + j];
        bool pred = ((eb >> (j & 63)) & 1) && (j != i) && (f >= 0.f);
        u64 word = __ballot(pred);
        if (lane == 0) A1w[i * NW + q * 4 + wv] = word;
    }
}

// ---------- fused: boolean A1@A1 (A2/CL/colAny) + cluster scores ----------
__global__ __launch_bounds__(256) void k_paths2s(const u64* __restrict__ A1w,
                                                 const float* __restrict__ fit,
                                                 u64* __restrict__ A2w, u64* __restrict__ CLw,
                                                 u64* colAny, float* cs) {
    int i = blockIdx.x;
    __shared__ u64 rowA[NW];
    __shared__ u64 rowA2[NW];
    __shared__ u64 part[8][NW];
    int t = threadIdx.x;
    if (t < NW) rowA[t] = A1w[i * NW + t];
    __syncthreads();
    int g = t >> 5, w = t & 31;
    u64 acc = 0;
    for (int ww = 0; ww < 4; ww++) {
        u64 bits = rowA[g * 4 + ww];
        int kbase = (g * 4 + ww) * 64;
        while (bits) {
            int k = __ffsll((unsigned long long)bits) - 1;
            bits &= bits - 1;
            acc |= A1w[(size_t)(kbase + k) * NW + w];
        }
    }
    part[g][w] = acc;
    __syncthreads();
    if (g == 0) {
        u64 p2 = part[0][w];
#pragma unroll
        for (int gg = 1; gg < 8; gg++) p2 |= part[gg][w];
        if ((i >> 6) == w) p2 &= ~(1ull << (i & 63));   // zero diagonal of A1@A1
        u64 a1 = rowA[w];
        u64 a2 = p2 & ~a1;
        u64 cl = a1 | a2;
        A2w[i * NW + w] = a2;
        CLw[i * NW + w] = cl;
        rowA2[w] = a2;
        atomicOr(&colAny[w], cl);
    }
    __syncthreads();
    // scores over fit row i using rowA / rowA2 in LDS
    float s1 = 0.f, s2 = 0.f;
    int d1 = 0, d2 = 0;
    for (int q = 0; q < 8; q++) {
        int j = q * 256 + t;
        float f = fit[(size_t)i * NN + j];
        int ww = j >> 6, b = j & 63;
        u64 a1 = rowA[ww], a2 = rowA2[ww];
        if ((a1 >> b) & 1) { s1 += f; d1++; }
        if ((a2 >> b) & 1) { s2 += f; d2++; }
    }
    for (int off = 32; off; off >>= 1) {
        s1 += __shfl_down(s1, off);
        s2 += __shfl_down(s2, off);
        d1 += __shfl_down(d1, off);
        d2 += __shfl_down(d2, off);
    }
    __shared__ float rs1[4], rs2[4];
    __shared__ int rd1[4], rd2[4];
    int wid = t >> 6, lane = t & 63;
    if (lane == 0) { rs1[wid] = s1; rs2[wid] = s2; rd1[wid] = d1; rd2[wid] = d2; }
    __syncthreads();
    if (t == 0) {
        float S1 = 0.f, S2 = 0.f; int D1 = 0, D2 = 0;
        for (int w2 = 0; w2 < 4; w2++) { S1 += rs1[w2]; S2 += rs2[w2]; D1 += rd1[w2]; D2 += rd2[w2]; }
        float v1 = D1 > 0 ? S1 / (float)D1 : 0.f;
        float v2 = D2 > 0 ? S2 / (float)D2 : 0.f;
        cs[i] = 0.5f * (v1 + v2);
    }
}

// ---------- local extrema ----------
__global__ __launch_bounds__(256) void k_extrema(const u64* __restrict__ A1w,
                                                 const float* __restrict__ cs,
                                                 unsigned char* is_c, u64* centerBits) {
    int i = blockIdx.x, t = threadIdx.x;
    float ci = cs[i];
    int ok = 1;
    for (int q = 0; q < 8; q++) {
        int j = q * 256 + t;
        u64 a1 = A1w[i * NW + (j >> 6)];
        float other = ((a1 >> (j & 63)) & 1) ? cs[j] : 0.0f;
        ok &= ((ci - other) > 0.0f) ? 1 : 0;
    }
    int all = __syncthreads_and(ok);
    if (t == 0) {
        is_c[i] = (unsigned char)(all ? 1 : 0);
        if (all) atomicOr(&centerBits[i >> 6], 1ull << (i & 63));
    }
}

// ---------- pooled: sparse-column M^T @ emb, 16-deep prefetch gather ----------
__global__ __launch_bounds__(256) void k_pooled(const float* __restrict__ fit,
                                                const float* __restrict__ emb,
                                                const u64* __restrict__ CLw,
                                                const u64* __restrict__ centerBits,
                                                const u64* __restrict__ colAny,
                                                const unsigned char* __restrict__ is_c,
                                                float* __restrict__ out) {
    int j = blockIdx.x;
    int t = threadIdx.x;
    bool red = ((colAny[j >> 6] >> (j & 63)) & 1ull) == 0ull;
    for (int w = 0; w < NW; w++) red |= (CLw[(size_t)j * NW + w] & centerBits[w]) != 0ull;
    const float2* embj = reinterpret_cast<const float2*>(emb + (size_t)j * DD);
    float2* outj = reinterpret_cast<float2*>(out + (size_t)j * DD);
    bool active = is_c[j] && !red;
    if (!active) {
        float dg = red ? 0.0f : 1.0f;
        float2 v = embj[t];
        float2 o; o.x = v.x * dg; o.y = v.y * dg;
        outj[t] = o;
        return;
    }
    // deterministic ordered compaction of column j's (i, weight) pairs
    __shared__ int lidx[NN];
    __shared__ float lwt[NN];
    __shared__ int wcnt[4];
    int wid = t >> 6, lane = t & 63;
    int wsh = j >> 6;
    u64 bmask = 1ull << (j & 63);
    int total = 0;
    for (int qq = 0; qq < 8; qq++) {
        int i = qq * 256 + t;
        u64 cw = CLw[(size_t)i * NW + wsh];
        bool p = (cw & bmask) != 0ull;
        float f = 0.f;
        if (p) f = fit[(size_t)i * NN + j];
        u64 mask = __ballot(p);
        if (lane == 0) wcnt[wid] = __popcll(mask);
        __syncthreads();
        int off = total;
        for (int w = 0; w < wid; w++) off += wcnt[w];
        int tq = wcnt[0] + wcnt[1] + wcnt[2] + wcnt[3];
        if (p) {
            int pos = off + __popcll(mask & ((1ull << lane) - 1ull));
            lidx[pos] = i;
            lwt[pos] = f;
        }
        total += tq;
        __syncthreads();
    }
    // gather with 16-deep software pipeline (hide ~200cy L2 latency)
    float2 acc = {0.f, 0.f};
    int k = 0;
    for (; k + 16 <= total; k += 16) {
        int idxr[16];
        float wtr[16];
#pragma unroll
        for (int u = 0; u < 16; u++) { idxr[u] = lidx[k + u]; wtr[u] = lwt[k + u]; }
        float2 e[16];
#pragma unroll
        for (int u = 0; u < 16; u++)
            e[u] = reinterpret_cast<const float2*>(emb + (size_t)idxr[u] * DD)[t];
#pragma unroll
        for (int u = 0; u < 16; u++) {
            acc.x += wtr[u] * e[u].x;
            acc.y += wtr[u] * e[u].y;
        }
    }
    for (; k < total; k++) {
        int i = lidx[k];
        float w = lwt[k];
        float2 e = reinterpret_cast<const float2*>(emb + (size_t)i * DD)[t];
        acc.x += w * e.x;
        acc.y += w * e.y;
    }
    float2 v = embj[t];      // diag term (dg=1 on active path)
    acc.x += v.x;
    acc.y += v.y;
    outj[t] = acc;
}

// ---------- launch ----------
extern "C" void kernel_launch(void* const* d_in, const int* in_sizes, int n_in,
                              void* d_out, int out_size, void* d_ws, size_t ws_size,
                              hipStream_t stream) {
    const float* emb = (const float*)d_in[0];
    const int*   ei  = (const int*)d_in[1];
    // d_in[2] = edge_matrix  (reconstructed from edge_index as a bitset)
    // d_in[3] = edge_matrix_weight (unused by reference math)
    const float* Wsc = (const float*)d_in[4];
    const float* bsc = (const float*)d_in[5];
    float* out = (float*)d_out;

    char* ws = (char*)d_ws;
    size_t off = 0;
    auto alloc = [&](size_t bytes) -> char* {
        char* p = ws + off;
        off = (off + bytes + 255) & ~(size_t)255;
        return p;
    };
    float* fit  = (float*)alloc((size_t)NN * NN * 4);      // 16 MB
    // zh/zl (4 MB) die after k_fitness; A1w/A2w/CLw born after -> alias
    char*  zblk = alloc((size_t)2 * NN * DD * 2);          // 4 MB shared region
    _Float16* zh = (_Float16*)zblk;
    _Float16* zl = (_Float16*)(zblk + (size_t)NN * DD * 2);
    u64* A1w = (u64*)zblk;
    u64* A2w = (u64*)(zblk + (size_t)NN * NW * 8);
    u64* CLw = (u64*)(zblk + (size_t)2 * NN * NW * 8);
    u64*   EBw        = (u64*)alloc((size_t)NN * NW * 8);  // live across fitness
    u64*   centerBits = (u64*)alloc(NW * 8);
    u64*   colAny     = (u64*)alloc(NW * 8);
    float* inv_norm   = (float*)alloc(NN * 4);
    float* av         = (float*)alloc(NN * 4);
    float* cv         = (float*)alloc(NN * 4);
    float* ssum       = (float*)alloc(NN * 4);
    float* cs         = (float*)alloc(NN * 4);
    u32*   mmax       = (u32*)alloc(NN * 4);
    unsigned char* is_c = (unsigned char*)alloc(NN);

    k_node<<<dim3(NN), dim3(256), 0, stream>>>(emb, Wsc, inv_norm, av, cv, zh, zl,
                                               mmax, ssum, centerBits, colAny, EBw);
    k_edgeA<<<dim3(EE / 256), dim3(256), 0, stream>>>(ei, av, cv, bsc, mmax, EBw);
    k_edge_sum<<<dim3(EE / 256), dim3(256), 0, stream>>>(ei, av, cv, bsc, mmax, ssum);
    k_fitness<<<dim3(NN / 128, NN / 128), dim3(256), 0, stream>>>(zh, zl, fit);
    k_edge_scatter<<<dim3(EE / 256), dim3(256), 0, stream>>>(ei, av, cv, bsc, mmax, ssum, fit);
    k_bits<<<dim3(NN), dim3(256), 0, stream>>>(EBw, fit, A1w);
    k_paths2s<<<dim3(NN), dim3(256), 0, stream>>>(A1w, fit, A2w, CLw, colAny, cs);
    k_extrema<<<dim3(NN), dim3(256), 0, stream>>>(A1w, cs, is_c, centerBits);
    k_pooled<<<dim3(NN), dim3(256), 0, stream>>>(fit, emb, CLw, centerBits, colAny, is_c, out);
}

// Round 5
// 164.271 us; speedup vs baseline: 2.3503x; 1.1881x over previous
//
#include <hip/hip_runtime.h>
#include <cstdint>
#include <cstddef>

typedef unsigned long long u64;
typedef unsigned int u32;
typedef _Float16 half8 __attribute__((ext_vector_type(8)));
typedef float f32x4 __attribute__((ext_vector_type(4)));

#define NN 2048
#define DD 512
#define EE 65536
#define NW 32   // 64-bit words per bitset row (2048/64)

// ---------- helpers ----------
__device__ __forceinline__ u32 fmap(float x) {
    u32 u = __float_as_uint(x);
    return (u & 0x80000000u) ? ~u : (u | 0x80000000u);
}
__device__ __forceinline__ float funmap(u32 u) {
    return (u & 0x80000000u) ? __uint_as_float(u ^ 0x80000000u) : __uint_as_float(~u);
}

// ---------- fused: init scratch + per-node reductions + f16 split ----------
__global__ __launch_bounds__(256) void k_node(const float* __restrict__ emb,
                                              const float* __restrict__ Wsc,
                                              float* inv_norm, float* av, float* cv,
                                              _Float16* __restrict__ zh,
                                              _Float16* __restrict__ zl,
                                              u32* mmax, float* ssum,
                                              u64* centerBits, u64* colAny, u64* EBw) {
    int n = blockIdx.x;
    int t = threadIdx.x;
    if (n < 256) EBw[n * 256 + t] = 0ull;
    else if (n < 264) { int idx = (n - 256) * 256 + t; mmax[idx] = 0u; ssum[idx] = 0.0f; }
    else if (n == 264 && t < NW) { centerBits[t] = 0ull; colAny[t] = 0ull; }

    const float* row = emb + (size_t)n * DD;
    float ss = 0.f, aa = 0.f, cc = 0.f;
    for (int d = t; d < DD; d += 256) {
        float v = row[d];
        ss += v * v;
        aa += v * Wsc[d];
        cc += v * Wsc[DD + d];
    }
    for (int off = 32; off; off >>= 1) {
        ss += __shfl_down(ss, off);
        aa += __shfl_down(aa, off);
        cc += __shfl_down(cc, off);
    }
    __shared__ float red[3][4];
    __shared__ float s_inv;
    int wid = t >> 6, lane = t & 63;
    if (lane == 0) { red[0][wid] = ss; red[1][wid] = aa; red[2][wid] = cc; }
    __syncthreads();
    if (t == 0) {
        float s = 0.f, a = 0.f, c = 0.f;
        for (int w = 0; w < 4; w++) { s += red[0][w]; a += red[1][w]; c += red[2][w]; }
        float iv = 1.0f / fmaxf(sqrtf(s), 1e-12f);
        inv_norm[n] = iv;
        s_inv = iv;
        av[n] = a;
        cv[n] = c;
    }
    __syncthreads();
    float iv = s_inv;
    for (int d = t; d < DD; d += 256) {
        float z = row[d] * iv;
        _Float16 h = (_Float16)z;
        _Float16 l = (_Float16)(z - (float)h);
        zh[(size_t)n * DD + d] = h;
        zl[(size_t)n * DD + d] = l;
    }
}

// ---------- edge passes ----------
__device__ __forceinline__ float edge_score(const int* ei, const float* av, const float* cv,
                                            float b0, int e, int* src, int* dst) {
    int s = ei[e], d = ei[EE + e];
    *src = s; *dst = d;
    float x = av[s] + cv[d] + b0;
    return x > 0.f ? x : 0.01f * x;   // leaky_relu
}

// fused: edge bitset + segment max
__global__ __launch_bounds__(256) void k_edgeA(const int* __restrict__ ei,
                                               const float* __restrict__ av,
                                               const float* __restrict__ cv,
                                               const float* __restrict__ bsc,
                                               u32* mmax, u64* EBw) {
    int e = blockIdx.x * 256 + threadIdx.x;
    if (e >= EE) return;
    int s, d;
    float x = edge_score(ei, av, cv, bsc[0], e, &s, &d);
    atomicMax(&mmax[s], fmap(x));
    atomicOr(&EBw[(size_t)s * NW + (d >> 6)], 1ull << (d & 63));
}

__global__ __launch_bounds__(256) void k_edge_sum(const int* __restrict__ ei,
                                                  const float* __restrict__ av,
                                                  const float* __restrict__ cv,
                                                  const float* __restrict__ bsc,
                                                  const u32* __restrict__ mmax, float* ssum) {
    int e = blockIdx.x * 256 + threadIdx.x;
    if (e >= EE) return;
    int s, d;
    float x = edge_score(ei, av, cv, bsc[0], e, &s, &d);
    float w = expf(x - funmap(mmax[s]));
    atomicAdd(&ssum[s], w);
}

__global__ __launch_bounds__(256) void k_edge_scatter(const int* __restrict__ ei,
                                                      const float* __restrict__ av,
                                                      const float* __restrict__ cv,
                                                      const float* __restrict__ bsc,
                                                      const u32* __restrict__ mmax,
                                                      const float* __restrict__ ssum,
                                                      float* fit) {
    int e = blockIdx.x * 256 + threadIdx.x;
    if (e >= EE) return;
    int s, d;
    float x = edge_score(ei, av, cv, bsc[0], e, &s, &d);
    float w = expf(x - funmap(mmax[s])) / (ssum[s] + 1e-16f);
    atomicAdd(&fit[(size_t)s * NN + d], w);
}

// ---------- fitness = Z Z^T via f16-split triple MFMA ----------
#define BK 64
__global__ __launch_bounds__(256) void k_fitness(const _Float16* __restrict__ zh,
                                                 const _Float16* __restrict__ zl,
                                                 float* __restrict__ fit) {
    __shared__ _Float16 Ah[128 * BK];
    __shared__ _Float16 Al[128 * BK];
    __shared__ _Float16 Bh[128 * BK];
    __shared__ _Float16 Bl[128 * BK];
    int tid = threadIdx.x;
    int wid = tid >> 6, lane = tid & 63;
    int wr = wid >> 1, wc = wid & 1;          // wave 2x2 grid of 64x64 sub-tiles
    int I = blockIdx.y * 128, J = blockIdx.x * 128;
    int lr = lane & 15;                        // frag row/col
    int q = lane >> 4;                         // k-group 0..3
    f32x4 acc[4][4] = {};
    for (int k0 = 0; k0 < DD; k0 += BK) {
        __syncthreads();
#pragma unroll
        for (int s = 0; s < 4; s++) {
            int id = (s << 8) + tid;
            int rl = id >> 3, sl = id & 7;
            int ks = ((sl ^ (rl & 7)) << 3);
            size_t gA = (size_t)(I + rl) * DD + k0 + ks;
            size_t gB = (size_t)(J + rl) * DD + k0 + ks;
            int lo = rl * BK + sl * 8;
            *reinterpret_cast<half8*>(&Ah[lo]) = *reinterpret_cast<const half8*>(&zh[gA]);
            *reinterpret_cast<half8*>(&Al[lo]) = *reinterpret_cast<const half8*>(&zl[gA]);
            *reinterpret_cast<half8*>(&Bh[lo]) = *reinterpret_cast<const half8*>(&zh[gB]);
            *reinterpret_cast<half8*>(&Bl[lo]) = *reinterpret_cast<const half8*>(&zl[gB]);
        }
        __syncthreads();
#pragma unroll
        for (int kk = 0; kk < 2; kk++) {
            half8 a_h[4], a_l[4], b_h[4], b_l[4];
#pragma unroll
            for (int f = 0; f < 4; f++) {
                int ra = wr * 64 + f * 16 + lr;
                int ca = (kk * 4 + q) ^ (ra & 7);
                int oa = ra * BK + ca * 8;
                a_h[f] = *reinterpret_cast<const half8*>(&Ah[oa]);
                a_l[f] = *reinterpret_cast<const half8*>(&Al[oa]);
                int rb = wc * 64 + f * 16 + lr;
                int cb = (kk * 4 + q) ^ (rb & 7);
                int ob = rb * BK + cb * 8;
                b_h[f] = *reinterpret_cast<const half8*>(&Bh[ob]);
                b_l[f] = *reinterpret_cast<const half8*>(&Bl[ob]);
            }
#pragma unroll
            for (int u = 0; u < 4; u++)
#pragma unroll
                for (int v = 0; v < 4; v++) {
                    acc[u][v] = __builtin_amdgcn_mfma_f32_16x16x32_f16(a_h[u], b_h[v], acc[u][v], 0, 0, 0);
                    acc[u][v] = __builtin_amdgcn_mfma_f32_16x16x32_f16(a_h[u], b_l[v], acc[u][v], 0, 0, 0);
                    acc[u][v] = __builtin_amdgcn_mfma_f32_16x16x32_f16(a_l[u], b_h[v], acc[u][v], 0, 0, 0);
                }
        }
    }
#pragma unroll
    for (int u = 0; u < 4; u++) {
        int r = I + wr * 64 + u * 16 + q * 4;
#pragma unroll
        for (int v = 0; v < 4; v++) {
            int c = J + wc * 64 + v * 16 + lr;
#pragma unroll
            for (int i2 = 0; i2 < 4; i2++)
                fit[(size_t)(r + i2) * NN + c] = acc[u][v][i2];
        }
    }
}

// ---------- A1 bitset: edge && !diag && fitness>=0 ----------
__global__ void k_bits(const u64* __restrict__ EBw, const float* __restrict__ fit,
                       u64* __restrict__ A1w) {
    int i = blockIdx.x;
    int t = threadIdx.x;
    int lane = t & 63, wv = t >> 6;
    for (int q = 0; q < 8; q++) {
        int j = q * 256 + t;
        u64 eb = EBw[(size_t)i * NW + (j >> 6)];
        float f = fit[(size_t)i * NN + j];
        bool pred = ((eb >> (j & 63)) & 1) && (j != i) && (f >= 0.f);
        u64 word = __ballot(pred);
        if (lane == 0) A1w[i * NW + q * 4 + wv] = word;
    }
}

// ---------- fused: boolean A1@A1 (A2/CL) + cluster scores (no colAny atomics) ----------
__global__ __launch_bounds__(256) void k_paths2s(const u64* __restrict__ A1w,
                                                 const float* __restrict__ fit,
                                                 u64* __restrict__ A2w, u64* __restrict__ CLw,
                                                 float* cs) {
    int i = blockIdx.x;
    __shared__ u64 rowA[NW];
    __shared__ u64 rowA2[NW];
    __shared__ u64 part[8][NW];
    int t = threadIdx.x;
    if (t < NW) rowA[t] = A1w[i * NW + t];
    __syncthreads();
    int g = t >> 5, w = t & 31;
    u64 acc = 0;
    for (int ww = 0; ww < 4; ww++) {
        u64 bits = rowA[g * 4 + ww];
        int kbase = (g * 4 + ww) * 64;
        while (bits) {
            int k = __ffsll((unsigned long long)bits) - 1;
            bits &= bits - 1;
            acc |= A1w[(size_t)(kbase + k) * NW + w];
        }
    }
    part[g][w] = acc;
    __syncthreads();
    if (g == 0) {
        u64 p2 = part[0][w];
#pragma unroll
        for (int gg = 1; gg < 8; gg++) p2 |= part[gg][w];
        if ((i >> 6) == w) p2 &= ~(1ull << (i & 63));   // zero diagonal of A1@A1
        u64 a1 = rowA[w];
        u64 a2 = p2 & ~a1;
        u64 cl = a1 | a2;
        A2w[i * NW + w] = a2;
        CLw[i * NW + w] = cl;
        rowA2[w] = a2;
    }
    __syncthreads();
    // scores over fit row i using rowA / rowA2 in LDS
    float s1 = 0.f, s2 = 0.f;
    int d1 = 0, d2 = 0;
    for (int q = 0; q < 8; q++) {
        int j = q * 256 + t;
        float f = fit[(size_t)i * NN + j];
        int ww = j >> 6, b = j & 63;
        u64 a1 = rowA[ww], a2 = rowA2[ww];
        if ((a1 >> b) & 1) { s1 += f; d1++; }
        if ((a2 >> b) & 1) { s2 += f; d2++; }
    }
    for (int off = 32; off; off >>= 1) {
        s1 += __shfl_down(s1, off);
        s2 += __shfl_down(s2, off);
        d1 += __shfl_down(d1, off);
        d2 += __shfl_down(d2, off);
    }
    __shared__ float rs1[4], rs2[4];
    __shared__ int rd1[4], rd2[4];
    int wid = t >> 6, lane = t & 63;
    if (lane == 0) { rs1[wid] = s1; rs2[wid] = s2; rd1[wid] = d1; rd2[wid] = d2; }
    __syncthreads();
    if (t == 0) {
        float S1 = 0.f, S2 = 0.f; int D1 = 0, D2 = 0;
        for (int w2 = 0; w2 < 4; w2++) { S1 += rs1[w2]; S2 += rs2[w2]; D1 += rd1[w2]; D2 += rd2[w2]; }
        float v1 = D1 > 0 ? S1 / (float)D1 : 0.f;
        float v2 = D2 > 0 ? S2 / (float)D2 : 0.f;
        cs[i] = 0.5f * (v1 + v2);
    }
}

// ---------- colAny = OR over rows of CLw (hierarchical, 1 atomic/word/block) ----------
__global__ __launch_bounds__(256) void k_colany(const u64* __restrict__ CLw, u64* colAny) {
    __shared__ u64 part[8][NW];
    int b = blockIdx.x;                 // 64 blocks x 32 rows
    int t = threadIdx.x;
    int sub = t >> 5, w = t & 31;
    u64 acc = 0;
#pragma unroll
    for (int k = 0; k < 4; k++) {
        int r = b * 32 + sub + k * 8;
        acc |= CLw[(size_t)r * NW + w];
    }
    part[sub][w] = acc;
    __syncthreads();
    if (t < NW) {
        u64 v = part[0][t];
#pragma unroll
        for (int s = 1; s < 8; s++) v |= part[s][t];
        atomicOr(&colAny[t], v);
    }
}

// ---------- local extrema ----------
__global__ __launch_bounds__(256) void k_extrema(const u64* __restrict__ A1w,
                                                 const float* __restrict__ cs,
                                                 unsigned char* is_c, u64* centerBits) {
    int i = blockIdx.x, t = threadIdx.x;
    float ci = cs[i];
    int ok = 1;
    for (int q = 0; q < 8; q++) {
        int j = q * 256 + t;
        u64 a1 = A1w[i * NW + (j >> 6)];
        float other = ((a1 >> (j & 63)) & 1) ? cs[j] : 0.0f;
        ok &= ((ci - other) > 0.0f) ? 1 : 0;
    }
    int all = __syncthreads_and(ok);
    if (t == 0) {
        is_c[i] = (unsigned char)(all ? 1 : 0);
        if (all) atomicOr(&centerBits[i >> 6], 1ull << (i & 63));
    }
}

// ---------- pooled: sparse-column M^T @ emb, 16-deep prefetch gather ----------
__global__ __launch_bounds__(256) void k_pooled(const float* __restrict__ fit,
                                                const float* __restrict__ emb,
                                                const u64* __restrict__ CLw,
                                                const u64* __restrict__ centerBits,
                                                const u64* __restrict__ colAny,
                                                const unsigned char* __restrict__ is_c,
                                                float* __restrict__ out) {
    int j = blockIdx.x;
    int t = threadIdx.x;
    bool red = ((colAny[j >> 6] >> (j & 63)) & 1ull) == 0ull;
    for (int w = 0; w < NW; w++) red |= (CLw[(size_t)j * NW + w] & centerBits[w]) != 0ull;
    const float2* embj = reinterpret_cast<const float2*>(emb + (size_t)j * DD);
    float2* outj = reinterpret_cast<float2*>(out + (size_t)j * DD);
    bool active = is_c[j] && !red;
    if (!active) {
        float dg = red ? 0.0f : 1.0f;
        float2 v = embj[t];
        float2 o; o.x = v.x * dg; o.y = v.y * dg;
        outj[t] = o;
        return;
    }
    // deterministic ordered compaction of column j's (i, weight) pairs
    __shared__ int lidx[NN];
    __shared__ float lwt[NN];
    __shared__ int wcnt[4];
    int wid = t >> 6, lane = t & 63;
    int wsh = j >> 6;
    u64 bmask = 1ull << (j & 63);
    int total = 0;
    for (int qq = 0; qq < 8; qq++) {
        int i = qq * 256 + t;
        u64 cw = CLw[(size_t)i * NW + wsh];
        bool p = (cw & bmask) != 0ull;
        float f = 0.f;
        if (p) f = fit[(size_t)i * NN + j];
        u64 mask = __ballot(p);
        if (lane == 0) wcnt[wid] = __popcll(mask);
        __syncthreads();
        int off = total;
        for (int w = 0; w < wid; w++) off += wcnt[w];
        int tq = wcnt[0] + wcnt[1] + wcnt[2] + wcnt[3];
        if (p) {
            int pos = off + __popcll(mask & ((1ull << lane) - 1ull));
            lidx[pos] = i;
            lwt[pos] = f;
        }
        total += tq;
        __syncthreads();
    }
    // gather with 16-deep software pipeline (hide ~200cy L2 latency)
    float2 acc = {0.f, 0.f};
    int k = 0;
    for (; k + 16 <= total; k += 16) {
        int idxr[16];
        float wtr[16];
#pragma unroll
        for (int u = 0; u < 16; u++) { idxr[u] = lidx[k + u]; wtr[u] = lwt[k + u]; }
        float2 e[16];
#pragma unroll
        for (int u = 0; u < 16; u++)
            e[u] = reinterpret_cast<const float2*>(emb + (size_t)idxr[u] * DD)[t];
#pragma unroll
        for (int u = 0; u < 16; u++) {
            acc.x += wtr[u] * e[u].x;
            acc.y += wtr[u] * e[u].y;
        }
    }
    for (; k < total; k++) {
        int i = lidx[k];
        float w = lwt[k];
        float2 e = reinterpret_cast<const float2*>(emb + (size_t)i * DD)[t];
        acc.x += w * e.x;
        acc.y += w * e.y;
    }
    float2 v = embj[t];      // diag term (dg=1 on active path)
    acc.x += v.x;
    acc.y += v.y;
    outj[t] = acc;
}

// ---------- launch ----------
extern "C" void kernel_launch(void* const* d_in, const int* in_sizes, int n_in,
                              void* d_out, int out_size, void* d_ws, size_t ws_size,
                              hipStream_t stream) {
    const float* emb = (const float*)d_in[0];
    const int*   ei  = (const int*)d_in[1];
    // d_in[2] = edge_matrix  (reconstructed from edge_index as a bitset)
    // d_in[3] = edge_matrix_weight (unused by reference math)
    const float* Wsc = (const float*)d_in[4];
    const float* bsc = (const float*)d_in[5];
    float* out = (float*)d_out;

    char* ws = (char*)d_ws;
    size_t off = 0;
    auto alloc = [&](size_t bytes) -> char* {
        char* p = ws + off;
        off = (off + bytes + 255) & ~(size_t)255;
        return p;
    };
    float* fit  = (float*)alloc((size_t)NN * NN * 4);      // 16 MB
    // zh/zl (4 MB) die after k_fitness; A1w/A2w/CLw born after -> alias
    char*  zblk = alloc((size_t)2 * NN * DD * 2);          // 4 MB shared region
    _Float16* zh = (_Float16*)zblk;
    _Float16* zl = (_Float16*)(zblk + (size_t)NN * DD * 2);
    u64* A1w = (u64*)zblk;
    u64* A2w = (u64*)(zblk + (size_t)NN * NW * 8);
    u64* CLw = (u64*)(zblk + (size_t)2 * NN * NW * 8);
    u64*   EBw        = (u64*)alloc((size_t)NN * NW * 8);  // live across fitness
    u64*   centerBits = (u64*)alloc(NW * 8);
    u64*   colAny     = (u64*)alloc(NW * 8);
    float* inv_norm   = (float*)alloc(NN * 4);
    float* av         = (float*)alloc(NN * 4);
    float* cv         = (float*)alloc(NN * 4);
    float* ssum       = (float*)alloc(NN * 4);
    float* cs         = (float*)alloc(NN * 4);
    u32*   mmax       = (u32*)alloc(NN * 4);
    unsigned char* is_c = (unsigned char*)alloc(NN);

    k_node<<<dim3(NN), dim3(256), 0, stream>>>(emb, Wsc, inv_norm, av, cv, zh, zl,
                                               mmax, ssum, centerBits, colAny, EBw);
    k_edgeA<<<dim3(EE / 256), dim3(256), 0, stream>>>(ei, av, cv, bsc, mmax, EBw);
    k_edge_sum<<<dim3(EE / 256), dim3(256), 0, stream>>>(ei, av, cv, bsc, mmax, ssum);
    k_fitness<<<dim3(NN / 128, NN / 128), dim3(256), 0, stream>>>(zh, zl, fit);
    k_edge_scatter<<<dim3(EE / 256), dim3(256), 0, stream>>>(ei, av, cv, bsc, mmax, ssum, fit);
    k_bits<<<dim3(NN), dim3(256), 0, stream>>>(EBw, fit, A1w);
    k_paths2s<<<dim3(NN), dim3(256), 0, stream>>>(A1w, fit, A2w, CLw, cs);
    k_colany<<<dim3(64), dim3(256), 0, stream>>>(CLw, colAny);
    k_extrema<<<dim3(NN), dim3(256), 0, stream>>>(A1w, cs, is_c, centerBits);
    k_pooled<<<dim3(NN), dim3(256), 0, stream>>>(fit, emb, CLw, centerBits, colAny, is_c, out);
}

// Round 6
// 157.282 us; speedup vs baseline: 2.4548x; 1.0444x over previous
//
#include <hip/hip_runtime.h>
#include <cstdint>
#include <cstddef>

typedef unsigned long long u64;
typedef unsigned int u32;
typedef _Float16 half8 __attribute__((ext_vector_type(8)));
typedef float f32x4 __attribute__((ext_vector_type(4)));

#define NN 2048
#define DD 512
#define EE 65536
#define NW 32   // 64-bit words per bitset row (2048/64)

// ---------- helpers ----------
__device__ __forceinline__ u32 fmap(float x) {
    u32 u = __float_as_uint(x);
    return (u & 0x80000000u) ? ~u : (u | 0x80000000u);
}
__device__ __forceinline__ float funmap(u32 u) {
    return (u & 0x80000000u) ? __uint_as_float(u ^ 0x80000000u) : __uint_as_float(~u);
}

// ---------- fused: init scratch + per-node reductions + f16 split ----------
__global__ __launch_bounds__(256) void k_node(const float* __restrict__ emb,
                                              const float* __restrict__ Wsc,
                                              float* inv_norm, float* av, float* cv,
                                              _Float16* __restrict__ zh,
                                              _Float16* __restrict__ zl,
                                              u32* mmax, float* ssum,
                                              u64* centerBits, u64* colAny, u64* EBw) {
    int n = blockIdx.x;
    int t = threadIdx.x;
    if (n < 256) EBw[n * 256 + t] = 0ull;
    else if (n < 264) { int idx = (n - 256) * 256 + t; mmax[idx] = 0u; ssum[idx] = 0.0f; }
    else if (n == 264 && t < NW) { centerBits[t] = 0ull; colAny[t] = 0ull; }

    const float* row = emb + (size_t)n * DD;
    float ss = 0.f, aa = 0.f, cc = 0.f;
    for (int d = t; d < DD; d += 256) {
        float v = row[d];
        ss += v * v;
        aa += v * Wsc[d];
        cc += v * Wsc[DD + d];
    }
    for (int off = 32; off; off >>= 1) {
        ss += __shfl_down(ss, off);
        aa += __shfl_down(aa, off);
        cc += __shfl_down(cc, off);
    }
    __shared__ float red[3][4];
    __shared__ float s_inv;
    int wid = t >> 6, lane = t & 63;
    if (lane == 0) { red[0][wid] = ss; red[1][wid] = aa; red[2][wid] = cc; }
    __syncthreads();
    if (t == 0) {
        float s = 0.f, a = 0.f, c = 0.f;
        for (int w = 0; w < 4; w++) { s += red[0][w]; a += red[1][w]; c += red[2][w]; }
        float iv = 1.0f / fmaxf(sqrtf(s), 1e-12f);
        inv_norm[n] = iv;
        s_inv = iv;
        av[n] = a;
        cv[n] = c;
    }
    __syncthreads();
    float iv = s_inv;
    for (int d = t; d < DD; d += 256) {
        float z = row[d] * iv;
        _Float16 h = (_Float16)z;
        _Float16 l = (_Float16)(z - (float)h);
        zh[(size_t)n * DD + d] = h;
        zl[(size_t)n * DD + d] = l;
    }
}

// ---------- edge passes ----------
__device__ __forceinline__ float edge_score(const int* ei, const float* av, const float* cv,
                                            float b0, int e, int* src, int* dst) {
    int s = ei[e], d = ei[EE + e];
    *src = s; *dst = d;
    float x = av[s] + cv[d] + b0;
    return x > 0.f ? x : 0.01f * x;   // leaky_relu
}

// fused: edge bitset + segment max
__global__ __launch_bounds__(256) void k_edgeA(const int* __restrict__ ei,
                                               const float* __restrict__ av,
                                               const float* __restrict__ cv,
                                               const float* __restrict__ bsc,
                                               u32* mmax, u64* EBw) {
    int e = blockIdx.x * 256 + threadIdx.x;
    if (e >= EE) return;
    int s, d;
    float x = edge_score(ei, av, cv, bsc[0], e, &s, &d);
    atomicMax(&mmax[s], fmap(x));
    atomicOr(&EBw[(size_t)s * NW + (d >> 6)], 1ull << (d & 63));
}

__global__ __launch_bounds__(256) void k_edge_sum(const int* __restrict__ ei,
                                                  const float* __restrict__ av,
                                                  const float* __restrict__ cv,
                                                  const float* __restrict__ bsc,
                                                  const u32* __restrict__ mmax, float* ssum) {
    int e = blockIdx.x * 256 + threadIdx.x;
    if (e >= EE) return;
    int s, d;
    float x = edge_score(ei, av, cv, bsc[0], e, &s, &d);
    float w = expf(x - funmap(mmax[s]));
    atomicAdd(&ssum[s], w);
}

__global__ __launch_bounds__(256) void k_edge_scatter(const int* __restrict__ ei,
                                                      const float* __restrict__ av,
                                                      const float* __restrict__ cv,
                                                      const float* __restrict__ bsc,
                                                      const u32* __restrict__ mmax,
                                                      const float* __restrict__ ssum,
                                                      float* fit) {
    int e = blockIdx.x * 256 + threadIdx.x;
    if (e >= EE) return;
    int s, d;
    float x = edge_score(ei, av, cv, bsc[0], e, &s, &d);
    float w = expf(x - funmap(mmax[s])) / (ssum[s] + 1e-16f);
    atomicAdd(&fit[(size_t)s * NN + d], w);
}

// ---------- fitness = Z Z^T via f16-split triple MFMA ----------
// 128x128 tile, 8 waves (2x4 grid of 64x32), BK=64, 64KB LDS,
// register-prefetch of next K-tile issued BEFORE compute (T14 split).
#define BK 64
__global__ __launch_bounds__(512) void k_fitness(const _Float16* __restrict__ zh,
                                                 const _Float16* __restrict__ zl,
                                                 float* __restrict__ fit) {
    __shared__ _Float16 Ah[128 * BK];
    __shared__ _Float16 Al[128 * BK];
    __shared__ _Float16 Bh[128 * BK];
    __shared__ _Float16 Bl[128 * BK];
    int tid = threadIdx.x;
    int wid = tid >> 6, lane = tid & 63;
    int wr = wid >> 2, wc = wid & 3;          // wave 2x4 grid of 64x32 sub-tiles
    int I = blockIdx.y * 128, J = blockIdx.x * 128;
    int lr = lane & 15;                        // frag row/col
    int q = lane >> 4;                         // k-group 0..3
    f32x4 acc[4][2] = {};

    // staging geometry: 2 chunks x 512 threads cover 1024 slots (row 0..127, slot 0..7)
    int rl0 = tid >> 3, sl0 = tid & 7;                 // chunk 0
    int rl1 = (512 + tid) >> 3, sl1 = tid & 7;         // chunk 1
    int ks0 = ((sl0 ^ (rl0 & 7)) << 3);
    int ks1 = ((sl1 ^ (rl1 & 7)) << 3);
    size_t gA0 = (size_t)(I + rl0) * DD + ks0, gB0 = (size_t)(J + rl0) * DD + ks0;
    size_t gA1 = (size_t)(I + rl1) * DD + ks1, gB1 = (size_t)(J + rl1) * DD + ks1;
    int lo0 = rl0 * BK + sl0 * 8, lo1 = rl1 * BK + sl1 * 8;

    // prologue: stage k0 = 0
    {
        half8 a0 = *reinterpret_cast<const half8*>(&zh[gA0]);
        half8 a1 = *reinterpret_cast<const half8*>(&zh[gA1]);
        half8 l0 = *reinterpret_cast<const half8*>(&zl[gA0]);
        half8 l1 = *reinterpret_cast<const half8*>(&zl[gA1]);
        half8 b0 = *reinterpret_cast<const half8*>(&zh[gB0]);
        half8 b1 = *reinterpret_cast<const half8*>(&zh[gB1]);
        half8 m0 = *reinterpret_cast<const half8*>(&zl[gB0]);
        half8 m1 = *reinterpret_cast<const half8*>(&zl[gB1]);
        *reinterpret_cast<half8*>(&Ah[lo0]) = a0;
        *reinterpret_cast<half8*>(&Ah[lo1]) = a1;
        *reinterpret_cast<half8*>(&Al[lo0]) = l0;
        *reinterpret_cast<half8*>(&Al[lo1]) = l1;
        *reinterpret_cast<half8*>(&Bh[lo0]) = b0;
        *reinterpret_cast<half8*>(&Bh[lo1]) = b1;
        *reinterpret_cast<half8*>(&Bl[lo0]) = m0;
        *reinterpret_cast<half8*>(&Bl[lo1]) = m1;
    }
    __syncthreads();

    for (int k0 = 0; k0 < DD; k0 += BK) {
        // issue next K-tile loads early (latency hides under MFMA below)
        half8 nA0, nA1, nAl0, nAl1, nB0, nB1, nBl0, nBl1;
        bool hasNext = (k0 + BK) < DD;
        if (hasNext) {
            int kn = k0 + BK;
            nA0  = *reinterpret_cast<const half8*>(&zh[gA0 + kn]);
            nA1  = *reinterpret_cast<const half8*>(&zh[gA1 + kn]);
            nAl0 = *reinterpret_cast<const half8*>(&zl[gA0 + kn]);
            nAl1 = *reinterpret_cast<const half8*>(&zl[gA1 + kn]);
            nB0  = *reinterpret_cast<const half8*>(&zh[gB0 + kn]);
            nB1  = *reinterpret_cast<const half8*>(&zh[gB1 + kn]);
            nBl0 = *reinterpret_cast<const half8*>(&zl[gB0 + kn]);
            nBl1 = *reinterpret_cast<const half8*>(&zl[gB1 + kn]);
        }
        // compute on current LDS tile
#pragma unroll
        for (int kk = 0; kk < 2; kk++) {
            half8 a_h[4], a_l[4], b_h[2], b_l[2];
#pragma unroll
            for (int f = 0; f < 4; f++) {
                int ra = wr * 64 + f * 16 + lr;
                int ca = (kk * 4 + q) ^ (ra & 7);
                int oa = ra * BK + ca * 8;
                a_h[f] = *reinterpret_cast<const half8*>(&Ah[oa]);
                a_l[f] = *reinterpret_cast<const half8*>(&Al[oa]);
            }
#pragma unroll
            for (int v = 0; v < 2; v++) {
                int rb = wc * 32 + v * 16 + lr;
                int cb = (kk * 4 + q) ^ (rb & 7);
                int ob = rb * BK + cb * 8;
                b_h[v] = *reinterpret_cast<const half8*>(&Bh[ob]);
                b_l[v] = *reinterpret_cast<const half8*>(&Bl[ob]);
            }
#pragma unroll
            for (int u = 0; u < 4; u++)
#pragma unroll
                for (int v = 0; v < 2; v++) {
                    acc[u][v] = __builtin_amdgcn_mfma_f32_16x16x32_f16(a_h[u], b_h[v], acc[u][v], 0, 0, 0);
                    acc[u][v] = __builtin_amdgcn_mfma_f32_16x16x32_f16(a_h[u], b_l[v], acc[u][v], 0, 0, 0);
                    acc[u][v] = __builtin_amdgcn_mfma_f32_16x16x32_f16(a_l[u], b_h[v], acc[u][v], 0, 0, 0);
                }
        }
        if (hasNext) {
            __syncthreads();
            *reinterpret_cast<half8*>(&Ah[lo0]) = nA0;
            *reinterpret_cast<half8*>(&Ah[lo1]) = nA1;
            *reinterpret_cast<half8*>(&Al[lo0]) = nAl0;
            *reinterpret_cast<half8*>(&Al[lo1]) = nAl1;
            *reinterpret_cast<half8*>(&Bh[lo0]) = nB0;
            *reinterpret_cast<half8*>(&Bh[lo1]) = nB1;
            *reinterpret_cast<half8*>(&Bl[lo0]) = nBl0;
            *reinterpret_cast<half8*>(&Bl[lo1]) = nBl1;
            __syncthreads();
        }
    }
    // epilogue: C/D layout col=lane&15, row=(lane>>4)*4+reg  (m89-verified)
#pragma unroll
    for (int u = 0; u < 4; u++) {
        int r = I + wr * 64 + u * 16 + q * 4;
#pragma unroll
        for (int v = 0; v < 2; v++) {
            int c = J + wc * 32 + v * 16 + lr;
#pragma unroll
            for (int i2 = 0; i2 < 4; i2++)
                fit[(size_t)(r + i2) * NN + c] = acc[u][v][i2];
        }
    }
}

// ---------- A1 bitset: edge && !diag && fitness>=0 ----------
__global__ void k_bits(const u64* __restrict__ EBw, const float* __restrict__ fit,
                       u64* __restrict__ A1w) {
    int i = blockIdx.x;
    int t = threadIdx.x;
    int lane = t & 63, wv = t >> 6;
    for (int q = 0; q < 8; q++) {
        int j = q * 256 + t;
        u64 eb = EBw[(size_t)i * NW + (j >> 6)];
        float f = fit[(size_t)i * NN + j];
        bool pred = ((eb >> (j & 63)) & 1) && (j != i) && (f >= 0.f);
        u64 word = __ballot(pred);
        if (lane == 0) A1w[i * NW + q * 4 + wv] = word;
    }
}

// ---------- fused: boolean A1@A1 (A2/CL) + cluster scores ----------
__global__ __launch_bounds__(256) void k_paths2s(const u64* __restrict__ A1w,
                                                 const float* __restrict__ fit,
                                                 u64* __restrict__ A2w, u64* __restrict__ CLw,
                                                 float* cs) {
    int i = blockIdx.x;
    __shared__ u64 rowA[NW];
    __shared__ u64 rowA2[NW];
    __shared__ u64 part[8][NW];
    int t = threadIdx.x;
    if (t < NW) rowA[t] = A1w[i * NW + t];
    __syncthreads();
    int g = t >> 5, w = t & 31;
    u64 acc = 0;
    for (int ww = 0; ww < 4; ww++) {
        u64 bits = rowA[g * 4 + ww];
        int kbase = (g * 4 + ww) * 64;
        while (bits) {
            int k = __ffsll((unsigned long long)bits) - 1;
            bits &= bits - 1;
            acc |= A1w[(size_t)(kbase + k) * NW + w];
        }
    }
    part[g][w] = acc;
    __syncthreads();
    if (g == 0) {
        u64 p2 = part[0][w];
#pragma unroll
        for (int gg = 1; gg < 8; gg++) p2 |= part[gg][w];
        if ((i >> 6) == w) p2 &= ~(1ull << (i & 63));   // zero diagonal of A1@A1
        u64 a1 = rowA[w];
        u64 a2 = p2 & ~a1;
        u64 cl = a1 | a2;
        A2w[i * NW + w] = a2;
        CLw[i * NW + w] = cl;
        rowA2[w] = a2;
    }
    __syncthreads();
    float s1 = 0.f, s2 = 0.f;
    int d1 = 0, d2 = 0;
    for (int q = 0; q < 8; q++) {
        int j = q * 256 + t;
        float f = fit[(size_t)i * NN + j];
        int ww = j >> 6, b = j & 63;
        u64 a1 = rowA[ww], a2 = rowA2[ww];
        if ((a1 >> b) & 1) { s1 += f; d1++; }
        if ((a2 >> b) & 1) { s2 += f; d2++; }
    }
    for (int off = 32; off; off >>= 1) {
        s1 += __shfl_down(s1, off);
        s2 += __shfl_down(s2, off);
        d1 += __shfl_down(d1, off);
        d2 += __shfl_down(d2, off);
    }
    __shared__ float rs1[4], rs2[4];
    __shared__ int rd1[4], rd2[4];
    int wid = t >> 6, lane = t & 63;
    if (lane == 0) { rs1[wid] = s1; rs2[wid] = s2; rd1[wid] = d1; rd2[wid] = d2; }
    __syncthreads();
    if (t == 0) {
        float S1 = 0.f, S2 = 0.f; int D1 = 0, D2 = 0;
        for (int w2 = 0; w2 < 4; w2++) { S1 += rs1[w2]; S2 += rs2[w2]; D1 += rd1[w2]; D2 += rd2[w2]; }
        float v1 = D1 > 0 ? S1 / (float)D1 : 0.f;
        float v2 = D2 > 0 ? S2 / (float)D2 : 0.f;
        cs[i] = 0.5f * (v1 + v2);
    }
}

// ---------- fused: local extrema + colAny reduction ----------
// all 2048 blocks: extrema for row i; blocks < 64 additionally OR-reduce
// their 32-row slice of CLw into colAny (1 atomic per word per block).
__global__ __launch_bounds__(256) void k_extcol(const u64* __restrict__ A1w,
                                                const u64* __restrict__ CLw,
                                                const float* __restrict__ cs,
                                                unsigned char* is_c, u64* centerBits,
                                                u64* colAny) {
    int i = blockIdx.x, t = threadIdx.x;
    __shared__ u64 part[8][NW];
    if (i < 64) {
        int sub = t >> 5, w = t & 31;
        u64 acc = 0;
#pragma unroll
        for (int k = 0; k < 4; k++) {
            int r = i * 32 + sub + k * 8;
            acc |= CLw[(size_t)r * NW + w];
        }
        part[sub][w] = acc;
    }
    float ci = cs[i];
    int ok = 1;
    for (int q = 0; q < 8; q++) {
        int j = q * 256 + t;
        u64 a1 = A1w[i * NW + (j >> 6)];
        float other = ((a1 >> (j & 63)) & 1) ? cs[j] : 0.0f;
        ok &= ((ci - other) > 0.0f) ? 1 : 0;
    }
    int all = __syncthreads_and(ok);
    if (t == 0) {
        is_c[i] = (unsigned char)(all ? 1 : 0);
        if (all) atomicOr(&centerBits[i >> 6], 1ull << (i & 63));
    }
    if (i < 64 && t < NW) {
        u64 v = part[0][t];
#pragma unroll
        for (int s = 1; s < 8; s++) v |= part[s][t];
        atomicOr(&colAny[t], v);
    }
}

// ---------- pooled: sparse-column M^T @ emb, 16-deep prefetch gather ----------
__global__ __launch_bounds__(256) void k_pooled(const float* __restrict__ fit,
                                                const float* __restrict__ emb,
                                                const u64* __restrict__ CLw,
                                                const u64* __restrict__ centerBits,
                                                const u64* __restrict__ colAny,
                                                const unsigned char* __restrict__ is_c,
                                                float* __restrict__ out) {
    int j = blockIdx.x;
    int t = threadIdx.x;
    bool red = ((colAny[j >> 6] >> (j & 63)) & 1ull) == 0ull;
    for (int w = 0; w < NW; w++) red |= (CLw[(size_t)j * NW + w] & centerBits[w]) != 0ull;
    const float2* embj = reinterpret_cast<const float2*>(emb + (size_t)j * DD);
    float2* outj = reinterpret_cast<float2*>(out + (size_t)j * DD);
    bool active = is_c[j] && !red;
    if (!active) {
        float dg = red ? 0.0f : 1.0f;
        float2 v = embj[t];
        float2 o; o.x = v.x * dg; o.y = v.y * dg;
        outj[t] = o;
        return;
    }
    __shared__ int lidx[NN];
    __shared__ float lwt[NN];
    __shared__ int wcnt[4];
    int wid = t >> 6, lane = t & 63;
    int wsh = j >> 6;
    u64 bmask = 1ull << (j & 63);
    int total = 0;
    for (int qq = 0; qq < 8; qq++) {
        int i = qq * 256 + t;
        u64 cw = CLw[(size_t)i * NW + wsh];
        bool p = (cw & bmask) != 0ull;
        float f = 0.f;
        if (p) f = fit[(size_t)i * NN + j];
        u64 mask = __ballot(p);
        if (lane == 0) wcnt[wid] = __popcll(mask);
        __syncthreads();
        int off = total;
        for (int w = 0; w < wid; w++) off += wcnt[w];
        int tq = wcnt[0] + wcnt[1] + wcnt[2] + wcnt[3];
        if (p) {
            int pos = off + __popcll(mask & ((1ull << lane) - 1ull));
            lidx[pos] = i;
            lwt[pos] = f;
        }
        total += tq;
        __syncthreads();
    }
    float2 acc = {0.f, 0.f};
    int k = 0;
    for (; k + 16 <= total; k += 16) {
        int idxr[16];
        float wtr[16];
#pragma unroll
        for (int u = 0; u < 16; u++) { idxr[u] = lidx[k + u]; wtr[u] = lwt[k + u]; }
        float2 e[16];
#pragma unroll
        for (int u = 0; u < 16; u++)
            e[u] = reinterpret_cast<const float2*>(emb + (size_t)idxr[u] * DD)[t];
#pragma unroll
        for (int u = 0; u < 16; u++) {
            acc.x += wtr[u] * e[u].x;
            acc.y += wtr[u] * e[u].y;
        }
    }
    for (; k < total; k++) {
        int i = lidx[k];
        float w = lwt[k];
        float2 e = reinterpret_cast<const float2*>(emb + (size_t)i * DD)[t];
        acc.x += w * e.x;
        acc.y += w * e.y;
    }
    float2 v = embj[t];
    acc.x += v.x;
    acc.y += v.y;
    outj[t] = acc;
}

// ---------- launch ----------
extern "C" void kernel_launch(void* const* d_in, const int* in_sizes, int n_in,
                              void* d_out, int out_size, void* d_ws, size_t ws_size,
                              hipStream_t stream) {
    const float* emb = (const float*)d_in[0];
    const int*   ei  = (const int*)d_in[1];
    // d_in[2] = edge_matrix  (reconstructed from edge_index as a bitset)
    // d_in[3] = edge_matrix_weight (unused by reference math)
    const float* Wsc = (const float*)d_in[4];
    const float* bsc = (const float*)d_in[5];
    float* out = (float*)d_out;

    char* ws = (char*)d_ws;
    size_t off = 0;
    auto alloc = [&](size_t bytes) -> char* {
        char* p = ws + off;
        off = (off + bytes + 255) & ~(size_t)255;
        return p;
    };
    float* fit  = (float*)alloc((size_t)NN * NN * 4);      // 16 MB
    // zh/zl (4 MB) die after k_fitness; A1w/A2w/CLw born after -> alias
    char*  zblk = alloc((size_t)2 * NN * DD * 2);          // 4 MB shared region
    _Float16* zh = (_Float16*)zblk;
    _Float16* zl = (_Float16*)(zblk + (size_t)NN * DD * 2);
    u64* A1w = (u64*)zblk;
    u64* A2w = (u64*)(zblk + (size_t)NN * NW * 8);
    u64* CLw = (u64*)(zblk + (size_t)2 * NN * NW * 8);
    u64*   EBw        = (u64*)alloc((size_t)NN * NW * 8);  // live across fitness
    u64*   centerBits = (u64*)alloc(NW * 8);
    u64*   colAny     = (u64*)alloc(NW * 8);
    float* inv_norm   = (float*)alloc(NN * 4);
    float* av         = (float*)alloc(NN * 4);
    float* cv         = (float*)alloc(NN * 4);
    float* ssum       = (float*)alloc(NN * 4);
    float* cs         = (float*)alloc(NN * 4);
    u32*   mmax       = (u32*)alloc(NN * 4);
    unsigned char* is_c = (unsigned char*)alloc(NN);

    k_node<<<dim3(NN), dim3(256), 0, stream>>>(emb, Wsc, inv_norm, av, cv, zh, zl,
                                               mmax, ssum, centerBits, colAny, EBw);
    k_edgeA<<<dim3(EE / 256), dim3(256), 0, stream>>>(ei, av, cv, bsc, mmax, EBw);
    k_edge_sum<<<dim3(EE / 256), dim3(256), 0, stream>>>(ei, av, cv, bsc, mmax, ssum);
    k_fitness<<<dim3(NN / 128, NN / 128), dim3(512), 0, stream>>>(zh, zl, fit);
    k_edge_scatter<<<dim3(EE / 256), dim3(256), 0, stream>>>(ei, av, cv, bsc, mmax, ssum, fit);
    k_bits<<<dim3(NN), dim3(256), 0, stream>>>(EBw, fit, A1w);
    k_paths2s<<<dim3(NN), dim3(256), 0, stream>>>(A1w, fit, A2w, CLw, cs);
    k_extcol<<<dim3(NN), dim3(256), 0, stream>>>(A1w, CLw, cs, is_c, centerBits, colAny);
    k_pooled<<<dim3(NN), dim3(256), 0, stream>>>(fit, emb, CLw, centerBits, colAny, is_c, out);
}

// Round 7
// 148.878 us; speedup vs baseline: 2.5933x; 1.0565x over previous
//
#include <hip/hip_runtime.h>
#include <cstdint>
#include <cstddef>

typedef unsigned long long u64;
typedef unsigned int u32;
typedef _Float16 half8 __attribute__((ext_vector_type(8)));
typedef float f32x4 __attribute__((ext_vector_type(4)));

#define NN 2048
#define DD 512
#define EE 65536
#define NW 32   // 64-bit words per bitset row (2048/64)

// ---------- fused: init scratch + per-node reductions + f16 split ----------
__global__ __launch_bounds__(256) void k_node(const float* __restrict__ emb,
                                              const float* __restrict__ Wsc,
                                              float* inv_norm, float* av, float* cv,
                                              _Float16* __restrict__ zh,
                                              _Float16* __restrict__ zl,
                                              float* ssum,
                                              u64* centerBits, u64* colAny, u64* EBw) {
    int n = blockIdx.x;
    int t = threadIdx.x;
    if (n < 256) EBw[n * 256 + t] = 0ull;
    else if (n < 264) { int idx = (n - 256) * 256 + t; ssum[idx] = 0.0f; }
    else if (n == 264 && t < NW) { centerBits[t] = 0ull; colAny[t] = 0ull; }

    const float* row = emb + (size_t)n * DD;
    float ss = 0.f, aa = 0.f, cc = 0.f;
    for (int d = t; d < DD; d += 256) {
        float v = row[d];
        ss += v * v;
        aa += v * Wsc[d];
        cc += v * Wsc[DD + d];
    }
    for (int off = 32; off; off >>= 1) {
        ss += __shfl_down(ss, off);
        aa += __shfl_down(aa, off);
        cc += __shfl_down(cc, off);
    }
    __shared__ float red[3][4];
    __shared__ float s_inv;
    int wid = t >> 6, lane = t & 63;
    if (lane == 0) { red[0][wid] = ss; red[1][wid] = aa; red[2][wid] = cc; }
    __syncthreads();
    if (t == 0) {
        float s = 0.f, a = 0.f, c = 0.f;
        for (int w = 0; w < 4; w++) { s += red[0][w]; a += red[1][w]; c += red[2][w]; }
        float iv = 1.0f / fmaxf(sqrtf(s), 1e-12f);
        inv_norm[n] = iv;
        s_inv = iv;
        av[n] = a;
        cv[n] = c;
    }
    __syncthreads();
    float iv = s_inv;
    for (int d = t; d < DD; d += 256) {
        float z = row[d] * iv;
        _Float16 h = (_Float16)z;
        _Float16 l = (_Float16)(z - (float)h);
        zh[(size_t)n * DD + d] = h;
        zl[(size_t)n * DD + d] = l;
    }
}

// ---------- edge passes (max-free softmax: exp(x)/sum, |x|<~6 so safe) ----------
__device__ __forceinline__ float edge_score(const int* ei, const float* av, const float* cv,
                                            float b0, int e, int* src, int* dst) {
    int s = ei[e], d = ei[EE + e];
    *src = s; *dst = d;
    float x = av[s] + cv[d] + b0;
    return x > 0.f ? x : 0.01f * x;   // leaky_relu
}

// fused: edge bitset + exp-sum
__global__ __launch_bounds__(256) void k_edgeA(const int* __restrict__ ei,
                                               const float* __restrict__ av,
                                               const float* __restrict__ cv,
                                               const float* __restrict__ bsc,
                                               float* ssum, u64* EBw) {
    int e = blockIdx.x * 256 + threadIdx.x;
    if (e >= EE) return;
    int s, d;
    float x = edge_score(ei, av, cv, bsc[0], e, &s, &d);
    atomicAdd(&ssum[s], expf(x));
    atomicOr(&EBw[(size_t)s * NW + (d >> 6)], 1ull << (d & 63));
}

__global__ __launch_bounds__(256) void k_edge_scatter(const int* __restrict__ ei,
                                                      const float* __restrict__ av,
                                                      const float* __restrict__ cv,
                                                      const float* __restrict__ bsc,
                                                      const float* __restrict__ ssum,
                                                      float* fit) {
    int e = blockIdx.x * 256 + threadIdx.x;
    if (e >= EE) return;
    int s, d;
    float x = edge_score(ei, av, cv, bsc[0], e, &s, &d);
    float w = expf(x) / (ssum[s] + 1e-16f);
    atomicAdd(&fit[(size_t)s * NN + d], w);
}

// ---------- fitness = Z Z^T via f16-split triple MFMA, SYMMETRIC (upper tiles) ----------
// 136 blocks cover bi<=bj tiles; off-diagonal tiles mirror-write the bitwise-
// identical transpose via a per-wave padded LDS transpose (coalesced stores).
#define BK 64
__global__ __launch_bounds__(512) void k_fitness(const _Float16* __restrict__ zh,
                                                 const _Float16* __restrict__ zl,
                                                 float* __restrict__ fit) {
    __shared__ _Float16 SM[4 * 128 * BK];        // 64 KB, reused for transpose
    _Float16* Ah = SM;
    _Float16* Al = SM + 128 * BK;
    _Float16* Bh = SM + 2 * 128 * BK;
    _Float16* Bl = SM + 3 * 128 * BK;
    int tid = threadIdx.x;
    int wid = tid >> 6, lane = tid & 63;
    int wr = wid >> 2, wc = wid & 3;          // wave 2x4 grid of 64x32 sub-tiles
    // triangular tile decode: blockIdx.x -> (bi, bj), bi <= bj
    int p = blockIdx.x, bi = 0;
    while (p >= 16 - bi) { p -= 16 - bi; bi++; }
    int bj = bi + p;
    int I = bi * 128, J = bj * 128;
    int lr = lane & 15;                        // frag row/col
    int q = lane >> 4;                         // k-group 0..3
    f32x4 acc[4][2] = {};

    int rl0 = tid >> 3, sl0 = tid & 7;
    int rl1 = (512 + tid) >> 3, sl1 = tid & 7;
    int ks0 = ((sl0 ^ (rl0 & 7)) << 3);
    int ks1 = ((sl1 ^ (rl1 & 7)) << 3);
    size_t gA0 = (size_t)(I + rl0) * DD + ks0, gB0 = (size_t)(J + rl0) * DD + ks0;
    size_t gA1 = (size_t)(I + rl1) * DD + ks1, gB1 = (size_t)(J + rl1) * DD + ks1;
    int lo0 = rl0 * BK + sl0 * 8, lo1 = rl1 * BK + sl1 * 8;

    {
        half8 a0 = *reinterpret_cast<const half8*>(&zh[gA0]);
        half8 a1 = *reinterpret_cast<const half8*>(&zh[gA1]);
        half8 l0 = *reinterpret_cast<const half8*>(&zl[gA0]);
        half8 l1 = *reinterpret_cast<const half8*>(&zl[gA1]);
        half8 b0 = *reinterpret_cast<const half8*>(&zh[gB0]);
        half8 b1 = *reinterpret_cast<const half8*>(&zh[gB1]);
        half8 m0 = *reinterpret_cast<const half8*>(&zl[gB0]);
        half8 m1 = *reinterpret_cast<const half8*>(&zl[gB1]);
        *reinterpret_cast<half8*>(&Ah[lo0]) = a0;
        *reinterpret_cast<half8*>(&Ah[lo1]) = a1;
        *reinterpret_cast<half8*>(&Al[lo0]) = l0;
        *reinterpret_cast<half8*>(&Al[lo1]) = l1;
        *reinterpret_cast<half8*>(&Bh[lo0]) = b0;
        *reinterpret_cast<half8*>(&Bh[lo1]) = b1;
        *reinterpret_cast<half8*>(&Bl[lo0]) = m0;
        *reinterpret_cast<half8*>(&Bl[lo1]) = m1;
    }
    __syncthreads();

    for (int k0 = 0; k0 < DD; k0 += BK) {
        half8 nA0, nA1, nAl0, nAl1, nB0, nB1, nBl0, nBl1;
        bool hasNext = (k0 + BK) < DD;
        if (hasNext) {
            int kn = k0 + BK;
            nA0  = *reinterpret_cast<const half8*>(&zh[gA0 + kn]);
            nA1  = *reinterpret_cast<const half8*>(&zh[gA1 + kn]);
            nAl0 = *reinterpret_cast<const half8*>(&zl[gA0 + kn]);
            nAl1 = *reinterpret_cast<const half8*>(&zl[gA1 + kn]);
            nB0  = *reinterpret_cast<const half8*>(&zh[gB0 + kn]);
            nB1  = *reinterpret_cast<const half8*>(&zh[gB1 + kn]);
            nBl0 = *reinterpret_cast<const half8*>(&zl[gB0 + kn]);
            nBl1 = *reinterpret_cast<const half8*>(&zl[gB1 + kn]);
        }
#pragma unroll
        for (int kk = 0; kk < 2; kk++) {
            half8 a_h[4], a_l[4], b_h[2], b_l[2];
#pragma unroll
            for (int f = 0; f < 4; f++) {
                int ra = wr * 64 + f * 16 + lr;
                int ca = (kk * 4 + q) ^ (ra & 7);
                int oa = ra * BK + ca * 8;
                a_h[f] = *reinterpret_cast<const half8*>(&Ah[oa]);
                a_l[f] = *reinterpret_cast<const half8*>(&Al[oa]);
            }
#pragma unroll
            for (int v = 0; v < 2; v++) {
                int rb = wc * 32 + v * 16 + lr;
                int cb = (kk * 4 + q) ^ (rb & 7);
                int ob = rb * BK + cb * 8;
                b_h[v] = *reinterpret_cast<const half8*>(&Bh[ob]);
                b_l[v] = *reinterpret_cast<const half8*>(&Bl[ob]);
            }
#pragma unroll
            for (int u = 0; u < 4; u++)
#pragma unroll
                for (int v = 0; v < 2; v++) {
                    acc[u][v] = __builtin_amdgcn_mfma_f32_16x16x32_f16(a_h[u], b_h[v], acc[u][v], 0, 0, 0);
                    acc[u][v] = __builtin_amdgcn_mfma_f32_16x16x32_f16(a_h[u], b_l[v], acc[u][v], 0, 0, 0);
                    acc[u][v] = __builtin_amdgcn_mfma_f32_16x16x32_f16(a_l[u], b_h[v], acc[u][v], 0, 0, 0);
                }
        }
        if (hasNext) {
            __syncthreads();
            *reinterpret_cast<half8*>(&Ah[lo0]) = nA0;
            *reinterpret_cast<half8*>(&Ah[lo1]) = nA1;
            *reinterpret_cast<half8*>(&Al[lo0]) = nAl0;
            *reinterpret_cast<half8*>(&Al[lo1]) = nAl1;
            *reinterpret_cast<half8*>(&Bh[lo0]) = nB0;
            *reinterpret_cast<half8*>(&Bh[lo1]) = nB1;
            *reinterpret_cast<half8*>(&Bl[lo0]) = nBl0;
            *reinterpret_cast<half8*>(&Bl[lo1]) = nBl1;
            __syncthreads();
        }
    }
    // normal write: C/D layout col=lane&15, row=(lane>>4)*4+reg (m89-verified)
#pragma unroll
    for (int u = 0; u < 4; u++) {
        int r = I + wr * 64 + u * 16 + q * 4;
#pragma unroll
        for (int v = 0; v < 2; v++) {
            int c = J + wc * 32 + v * 16 + lr;
#pragma unroll
            for (int i2 = 0; i2 < 4; i2++)
                fit[(size_t)(r + i2) * NN + c] = acc[u][v][i2];
        }
    }
    // mirror write (exact transpose) via per-wave padded LDS transpose
    if (bi != bj) {
        __syncthreads();                         // staging reads all done
        float* Tw = reinterpret_cast<float*>(SM) + wid * 1040;   // [16][65]
#pragma unroll
        for (int v = 0; v < 2; v++) {
#pragma unroll
            for (int u = 0; u < 4; u++)
#pragma unroll
                for (int i2 = 0; i2 < 4; i2++)
                    Tw[lr * 65 + u * 16 + q * 4 + i2] = acc[u][v][i2];
            // wave-internal LDS: no barrier needed (compiler inserts lgkmcnt)
            int cbase = J + wc * 32 + v * 16;
            int rbase = I + wr * 64;
#pragma unroll
            for (int rr = 0; rr < 16; rr++) {
                float val = Tw[rr * 65 + lane];
                fit[(size_t)(cbase + rr) * NN + rbase + lane] = val;
            }
        }
    }
}

// ---------- A1 bitset: edge && !diag && fitness>=0 ----------
__global__ void k_bits(const u64* __restrict__ EBw, const float* __restrict__ fit,
                       u64* __restrict__ A1w) {
    int i = blockIdx.x;
    int t = threadIdx.x;
    int lane = t & 63, wv = t >> 6;
    for (int q = 0; q < 8; q++) {
        int j = q * 256 + t;
        u64 eb = EBw[(size_t)i * NW + (j >> 6)];
        float f = fit[(size_t)i * NN + j];
        bool pred = ((eb >> (j & 63)) & 1) && (j != i) && (f >= 0.f);
        u64 word = __ballot(pred);
        if (lane == 0) A1w[i * NW + q * 4 + wv] = word;
    }
}

// ---------- fused: boolean A1@A1 (A2/CL) + cluster scores ----------
__global__ __launch_bounds__(256) void k_paths2s(const u64* __restrict__ A1w,
                                                 const float* __restrict__ fit,
                                                 u64* __restrict__ A2w, u64* __restrict__ CLw,
                                                 float* cs) {
    int i = blockIdx.x;
    __shared__ u64 rowA[NW];
    __shared__ u64 rowA2[NW];
    __shared__ u64 part[8][NW];
    int t = threadIdx.x;
    if (t < NW) rowA[t] = A1w[i * NW + t];
    __syncthreads();
    int g = t >> 5, w = t & 31;
    u64 acc = 0;
    for (int ww = 0; ww < 4; ww++) {
        u64 bits = rowA[g * 4 + ww];
        int kbase = (g * 4 + ww) * 64;
        while (bits) {
            int k = __ffsll((unsigned long long)bits) - 1;
            bits &= bits - 1;
            acc |= A1w[(size_t)(kbase + k) * NW + w];
        }
    }
    part[g][w] = acc;
    __syncthreads();
    if (g == 0) {
        u64 p2 = part[0][w];
#pragma unroll
        for (int gg = 1; gg < 8; gg++) p2 |= part[gg][w];
        if ((i >> 6) == w) p2 &= ~(1ull << (i & 63));   // zero diagonal of A1@A1
        u64 a1 = rowA[w];
        u64 a2 = p2 & ~a1;
        u64 cl = a1 | a2;
        A2w[i * NW + w] = a2;
        CLw[i * NW + w] = cl;
        rowA2[w] = a2;
    }
    __syncthreads();
    float s1 = 0.f, s2 = 0.f;
    int d1 = 0, d2 = 0;
    for (int q = 0; q < 8; q++) {
        int j = q * 256 + t;
        float f = fit[(size_t)i * NN + j];
        int ww = j >> 6, b = j & 63;
        u64 a1 = rowA[ww], a2 = rowA2[ww];
        if ((a1 >> b) & 1) { s1 += f; d1++; }
        if ((a2 >> b) & 1) { s2 += f; d2++; }
    }
    for (int off = 32; off; off >>= 1) {
        s1 += __shfl_down(s1, off);
        s2 += __shfl_down(s2, off);
        d1 += __shfl_down(d1, off);
        d2 += __shfl_down(d2, off);
    }
    __shared__ float rs1[4], rs2[4];
    __shared__ int rd1[4], rd2[4];
    int wid = t >> 6, lane = t & 63;
    if (lane == 0) { rs1[wid] = s1; rs2[wid] = s2; rd1[wid] = d1; rd2[wid] = d2; }
    __syncthreads();
    if (t == 0) {
        float S1 = 0.f, S2 = 0.f; int D1 = 0, D2 = 0;
        for (int w2 = 0; w2 < 4; w2++) { S1 += rs1[w2]; S2 += rs2[w2]; D1 += rd1[w2]; D2 += rd2[w2]; }
        float v1 = D1 > 0 ? S1 / (float)D1 : 0.f;
        float v2 = D2 > 0 ? S2 / (float)D2 : 0.f;
        cs[i] = 0.5f * (v1 + v2);
    }
}

// ---------- fused: local extrema + colAny reduction ----------
__global__ __launch_bounds__(256) void k_extcol(const u64* __restrict__ A1w,
                                                const u64* __restrict__ CLw,
                                                const float* __restrict__ cs,
                                                unsigned char* is_c, u64* centerBits,
                                                u64* colAny) {
    int i = blockIdx.x, t = threadIdx.x;
    __shared__ u64 part[8][NW];
    if (i < 64) {
        int sub = t >> 5, w = t & 31;
        u64 acc = 0;
#pragma unroll
        for (int k = 0; k < 4; k++) {
            int r = i * 32 + sub + k * 8;
            acc |= CLw[(size_t)r * NW + w];
        }
        part[sub][w] = acc;
    }
    float ci = cs[i];
    int ok = 1;
    for (int q = 0; q < 8; q++) {
        int j = q * 256 + t;
        u64 a1 = A1w[i * NW + (j >> 6)];
        float other = ((a1 >> (j & 63)) & 1) ? cs[j] : 0.0f;
        ok &= ((ci - other) > 0.0f) ? 1 : 0;
    }
    int all = __syncthreads_and(ok);
    if (t == 0) {
        is_c[i] = (unsigned char)(all ? 1 : 0);
        if (all) atomicOr(&centerBits[i >> 6], 1ull << (i & 63));
    }
    if (i < 64 && t < NW) {
        u64 v = part[0][t];
#pragma unroll
        for (int s = 1; s < 8; s++) v |= part[s][t];
        atomicOr(&colAny[t], v);
    }
}

// ---------- pooled: sparse-column M^T @ emb, 16-deep prefetch gather ----------
__global__ __launch_bounds__(256) void k_pooled(const float* __restrict__ fit,
                                                const float* __restrict__ emb,
                                                const u64* __restrict__ CLw,
                                                const u64* __restrict__ centerBits,
                                                const u64* __restrict__ colAny,
                                                const unsigned char* __restrict__ is_c,
                                                float* __restrict__ out) {
    int j = blockIdx.x;
    int t = threadIdx.x;
    bool red = ((colAny[j >> 6] >> (j & 63)) & 1ull) == 0ull;
    for (int w = 0; w < NW; w++) red |= (CLw[(size_t)j * NW + w] & centerBits[w]) != 0ull;
    const float2* embj = reinterpret_cast<const float2*>(emb + (size_t)j * DD);
    float2* outj = reinterpret_cast<float2*>(out + (size_t)j * DD);
    bool active = is_c[j] && !red;
    if (!active) {
        float dg = red ? 0.0f : 1.0f;
        float2 v = embj[t];
        float2 o; o.x = v.x * dg; o.y = v.y * dg;
        outj[t] = o;
        return;
    }
    __shared__ int lidx[NN];
    __shared__ float lwt[NN];
    __shared__ int wcnt[4];
    int wid = t >> 6, lane = t & 63;
    int wsh = j >> 6;
    u64 bmask = 1ull << (j & 63);
    int total = 0;
    for (int qq = 0; qq < 8; qq++) {
        int i = qq * 256 + t;
        u64 cw = CLw[(size_t)i * NW + wsh];
        bool p = (cw & bmask) != 0ull;
        float f = 0.f;
        if (p) f = fit[(size_t)i * NN + j];
        u64 mask = __ballot(p);
        if (lane == 0) wcnt[wid] = __popcll(mask);
        __syncthreads();
        int off = total;
        for (int w = 0; w < wid; w++) off += wcnt[w];
        int tq = wcnt[0] + wcnt[1] + wcnt[2] + wcnt[3];
        if (p) {
            int pos = off + __popcll(mask & ((1ull << lane) - 1ull));
            lidx[pos] = i;
            lwt[pos] = f;
        }
        total += tq;
        __syncthreads();
    }
    float2 acc = {0.f, 0.f};
    int k = 0;
    for (; k + 16 <= total; k += 16) {
        int idxr[16];
        float wtr[16];
#pragma unroll
        for (int u = 0; u < 16; u++) { idxr[u] = lidx[k + u]; wtr[u] = lwt[k + u]; }
        float2 e[16];
#pragma unroll
        for (int u = 0; u < 16; u++)
            e[u] = reinterpret_cast<const float2*>(emb + (size_t)idxr[u] * DD)[t];
#pragma unroll
        for (int u = 0; u < 16; u++) {
            acc.x += wtr[u] * e[u].x;
            acc.y += wtr[u] * e[u].y;
        }
    }
    for (; k < total; k++) {
        int i = lidx[k];
        float w = lwt[k];
        float2 e = reinterpret_cast<const float2*>(emb + (size_t)i * DD)[t];
        acc.x += w * e.x;
        acc.y += w * e.y;
    }
    float2 v = embj[t];
    acc.x += v.x;
    acc.y += v.y;
    outj[t] = acc;
}

// ---------- launch ----------
extern "C" void kernel_launch(void* const* d_in, const int* in_sizes, int n_in,
                              void* d_out, int out_size, void* d_ws, size_t ws_size,
                              hipStream_t stream) {
    const float* emb = (const float*)d_in[0];
    const int*   ei  = (const int*)d_in[1];
    // d_in[2] = edge_matrix  (reconstructed from edge_index as a bitset)
    // d_in[3] = edge_matrix_weight (unused by reference math)
    const float* Wsc = (const float*)d_in[4];
    const float* bsc = (const float*)d_in[5];
    float* out = (float*)d_out;

    char* ws = (char*)d_ws;
    size_t off = 0;
    auto alloc = [&](size_t bytes) -> char* {
        char* p = ws + off;
        off = (off + bytes + 255) & ~(size_t)255;
        return p;
    };
    float* fit  = (float*)alloc((size_t)NN * NN * 4);      // 16 MB
    // zh/zl (4 MB) die after k_fitness; A1w/A2w/CLw born after -> alias
    char*  zblk = alloc((size_t)2 * NN * DD * 2);          // 4 MB shared region
    _Float16* zh = (_Float16*)zblk;
    _Float16* zl = (_Float16*)(zblk + (size_t)NN * DD * 2);
    u64* A1w = (u64*)zblk;
    u64* A2w = (u64*)(zblk + (size_t)NN * NW * 8);
    u64* CLw = (u64*)(zblk + (size_t)2 * NN * NW * 8);
    u64*   EBw        = (u64*)alloc((size_t)NN * NW * 8);  // live across fitness
    u64*   centerBits = (u64*)alloc(NW * 8);
    u64*   colAny     = (u64*)alloc(NW * 8);
    float* inv_norm   = (float*)alloc(NN * 4);
    float* av         = (float*)alloc(NN * 4);
    float* cv         = (float*)alloc(NN * 4);
    float* ssum       = (float*)alloc(NN * 4);
    float* cs         = (float*)alloc(NN * 4);
    unsigned char* is_c = (unsigned char*)alloc(NN);

    k_node<<<dim3(NN), dim3(256), 0, stream>>>(emb, Wsc, inv_norm, av, cv, zh, zl,
                                               ssum, centerBits, colAny, EBw);
    k_edgeA<<<dim3(EE / 256), dim3(256), 0, stream>>>(ei, av, cv, bsc, ssum, EBw);
    k_fitness<<<dim3(136), dim3(512), 0, stream>>>(zh, zl, fit);
    k_edge_scatter<<<dim3(EE / 256), dim3(256), 0, stream>>>(ei, av, cv, bsc, ssum, fit);
    k_bits<<<dim3(NN), dim3(256), 0, stream>>>(EBw, fit, A1w);
    k_paths2s<<<dim3(NN), dim3(256), 0, stream>>>(A1w, fit, A2w, CLw, cs);
    k_extcol<<<dim3(NN), dim3(256), 0, stream>>>(A1w, CLw, cs, is_c, centerBits, colAny);
    k_pooled<<<dim3(NN), dim3(256), 0, stream>>>(fit, emb, CLw, centerBits, colAny, is_c, out);
}

// Round 10
// 146.208 us; speedup vs baseline: 2.6407x; 1.0183x over previous
//
#include <hip/hip_runtime.h>
#include <cstdint>
#include <cstddef>

typedef unsigned long long u64;
typedef unsigned int u32;
typedef _Float16 half8 __attribute__((ext_vector_type(8)));
typedef float f32x4 __attribute__((ext_vector_type(4)));

#define NN 2048
#define DD 512
#define EE 65536
#define NW 32   // 64-bit words per bitset row (2048/64)

// ---------- fused: init scratch + per-node reductions + f16 split ----------
__global__ __launch_bounds__(256) void k_node(const float* __restrict__ emb,
                                              const float* __restrict__ Wsc,
                                              float* inv_norm, float* av, float* cv,
                                              _Float16* __restrict__ zh,
                                              _Float16* __restrict__ zl,
                                              float* ssum,
                                              u64* centerBits, u64* colAny, u64* EBw) {
    int n = blockIdx.x;
    int t = threadIdx.x;
    if (n < 256) EBw[n * 256 + t] = 0ull;
    else if (n < 264) { int idx = (n - 256) * 256 + t; ssum[idx] = 0.0f; }
    else if (n == 264 && t < NW) { centerBits[t] = 0ull; colAny[t] = 0ull; }

    const float* row = emb + (size_t)n * DD;
    float ss = 0.f, aa = 0.f, cc = 0.f;
    for (int d = t; d < DD; d += 256) {
        float v = row[d];
        ss += v * v;
        aa += v * Wsc[d];
        cc += v * Wsc[DD + d];
    }
    for (int off = 32; off; off >>= 1) {
        ss += __shfl_down(ss, off);
        aa += __shfl_down(aa, off);
        cc += __shfl_down(cc, off);
    }
    __shared__ float red[3][4];
    __shared__ float s_inv;
    int wid = t >> 6, lane = t & 63;
    if (lane == 0) { red[0][wid] = ss; red[1][wid] = aa; red[2][wid] = cc; }
    __syncthreads();
    if (t == 0) {
        float s = 0.f, a = 0.f, c = 0.f;
        for (int w = 0; w < 4; w++) { s += red[0][w]; a += red[1][w]; c += red[2][w]; }
        float iv = 1.0f / fmaxf(sqrtf(s), 1e-12f);
        inv_norm[n] = iv;
        s_inv = iv;
        av[n] = a;
        cv[n] = c;
    }
    __syncthreads();
    float iv = s_inv;
    for (int d = t; d < DD; d += 256) {
        float z = row[d] * iv;
        _Float16 h = (_Float16)z;
        _Float16 l = (_Float16)(z - (float)h);
        zh[(size_t)n * DD + d] = h;
        zl[(size_t)n * DD + d] = l;
    }
}

// ---------- edge passes (max-free softmax: exp(x)/sum, |x|<~6 so safe) ----------
__device__ __forceinline__ float edge_score(const int* ei, const float* av, const float* cv,
                                            float b0, int e, int* src, int* dst) {
    int s = ei[e], d = ei[EE + e];
    *src = s; *dst = d;
    float x = av[s] + cv[d] + b0;
    return x > 0.f ? x : 0.01f * x;   // leaky_relu
}

// fused: edge bitset + exp-sum
__global__ __launch_bounds__(256) void k_edgeA(const int* __restrict__ ei,
                                               const float* __restrict__ av,
                                               const float* __restrict__ cv,
                                               const float* __restrict__ bsc,
                                               float* ssum, u64* EBw) {
    int e = blockIdx.x * 256 + threadIdx.x;
    if (e >= EE) return;
    int s, d;
    float x = edge_score(ei, av, cv, bsc[0], e, &s, &d);
    atomicAdd(&ssum[s], expf(x));
    atomicOr(&EBw[(size_t)s * NW + (d >> 6)], 1ull << (d & 63));
}

__global__ __launch_bounds__(256) void k_edge_scatter(const int* __restrict__ ei,
                                                      const float* __restrict__ av,
                                                      const float* __restrict__ cv,
                                                      const float* __restrict__ bsc,
                                                      const float* __restrict__ ssum,
                                                      float* fit) {
    int e = blockIdx.x * 256 + threadIdx.x;
    if (e >= EE) return;
    int s, d;
    float x = edge_score(ei, av, cv, bsc[0], e, &s, &d);
    float w = expf(x) / (ssum[s] + 1e-16f);
    atomicAdd(&fit[(size_t)s * NN + d], w);
}

// ---------- fitness = Z Z^T via f16-split triple MFMA, SYMMETRIC 64x64 tiles ----------
// 528 blocks (32x33/2 upper-triangle), 256 thr (4 waves, 2x2 of 32x32), 32KB LDS.
// ~2 blocks/CU -> all CUs busy + inter-block latency overlap.
#define BK 64
__global__ __launch_bounds__(256) void k_fitness(const _Float16* __restrict__ zh,
                                                 const _Float16* __restrict__ zl,
                                                 float* __restrict__ fit) {
    __shared__ _Float16 SM[4 * 64 * BK];        // 32 KB, reused for transpose
    _Float16* Ah = SM;
    _Float16* Al = SM + 64 * BK;
    _Float16* Bh = SM + 2 * 64 * BK;
    _Float16* Bl = SM + 3 * 64 * BK;
    int tid = threadIdx.x;
    int wid = tid >> 6, lane = tid & 63;
    int wr = wid >> 1, wc = wid & 1;           // wave 2x2 grid of 32x32 sub-tiles
    // triangular tile decode: blockIdx.x -> (bi, bj), bi <= bj, 32 tile-rows
    int p = blockIdx.x, bi = 0;
    while (p >= 32 - bi) { p -= 32 - bi; bi++; }
    int bj = bi + p;
    int I = bi * 64, J = bj * 64;
    int lr = lane & 15;                        // frag row/col
    int q = lane >> 4;                         // k-group 0..3
    f32x4 acc[2][2] = {};

    // staging: 64 rows x 8 slots = 512 slots -> 2 chunks of 256 threads
    int rl0 = tid >> 3, sl0 = tid & 7;                 // chunk 0 (rows 0..31)
    int rl1 = (256 + tid) >> 3, sl1 = tid & 7;         // chunk 1 (rows 32..63)
    int ks0 = ((sl0 ^ (rl0 & 7)) << 3);
    int ks1 = ((sl1 ^ (rl1 & 7)) << 3);
    size_t gA0 = (size_t)(I + rl0) * DD + ks0, gB0 = (size_t)(J + rl0) * DD + ks0;
    size_t gA1 = (size_t)(I + rl1) * DD + ks1, gB1 = (size_t)(J + rl1) * DD + ks1;
    int lo0 = rl0 * BK + sl0 * 8, lo1 = rl1 * BK + sl1 * 8;

    {   // prologue: stage k0 = 0
        half8 a0 = *reinterpret_cast<const half8*>(&zh[gA0]);
        half8 a1 = *reinterpret_cast<const half8*>(&zh[gA1]);
        half8 l0 = *reinterpret_cast<const half8*>(&zl[gA0]);
        half8 l1 = *reinterpret_cast<const half8*>(&zl[gA1]);
        half8 b0 = *reinterpret_cast<const half8*>(&zh[gB0]);
        half8 b1 = *reinterpret_cast<const half8*>(&zh[gB1]);
        half8 m0 = *reinterpret_cast<const half8*>(&zl[gB0]);
        half8 m1 = *reinterpret_cast<const half8*>(&zl[gB1]);
        *reinterpret_cast<half8*>(&Ah[lo0]) = a0;
        *reinterpret_cast<half8*>(&Ah[lo1]) = a1;
        *reinterpret_cast<half8*>(&Al[lo0]) = l0;
        *reinterpret_cast<half8*>(&Al[lo1]) = l1;
        *reinterpret_cast<half8*>(&Bh[lo0]) = b0;
        *reinterpret_cast<half8*>(&Bh[lo1]) = b1;
        *reinterpret_cast<half8*>(&Bl[lo0]) = m0;
        *reinterpret_cast<half8*>(&Bl[lo1]) = m1;
    }
    __syncthreads();

    for (int k0 = 0; k0 < DD; k0 += BK) {
        half8 nA0, nA1, nAl0, nAl1, nB0, nB1, nBl0, nBl1;
        bool hasNext = (k0 + BK) < DD;
        if (hasNext) {
            int kn = k0 + BK;
            nA0  = *reinterpret_cast<const half8*>(&zh[gA0 + kn]);
            nA1  = *reinterpret_cast<const half8*>(&zh[gA1 + kn]);
            nAl0 = *reinterpret_cast<const half8*>(&zl[gA0 + kn]);
            nAl1 = *reinterpret_cast<const half8*>(&zl[gA1 + kn]);
            nB0  = *reinterpret_cast<const half8*>(&zh[gB0 + kn]);
            nB1  = *reinterpret_cast<const half8*>(&zh[gB1 + kn]);
            nBl0 = *reinterpret_cast<const half8*>(&zl[gB0 + kn]);
            nBl1 = *reinterpret_cast<const half8*>(&zl[gB1 + kn]);
        }
#pragma unroll
        for (int kk = 0; kk < 2; kk++) {
            half8 a_h[2], a_l[2], b_h[2], b_l[2];
#pragma unroll
            for (int f = 0; f < 2; f++) {
                int ra = wr * 32 + f * 16 + lr;
                int ca = (kk * 4 + q) ^ (ra & 7);
                int oa = ra * BK + ca * 8;
                a_h[f] = *reinterpret_cast<const half8*>(&Ah[oa]);
                a_l[f] = *reinterpret_cast<const half8*>(&Al[oa]);
                int rb = wc * 32 + f * 16 + lr;
                int cb = (kk * 4 + q) ^ (rb & 7);
                int ob = rb * BK + cb * 8;
                b_h[f] = *reinterpret_cast<const half8*>(&Bh[ob]);
                b_l[f] = *reinterpret_cast<const half8*>(&Bl[ob]);
            }
#pragma unroll
            for (int u = 0; u < 2; u++)
#pragma unroll
                for (int v = 0; v < 2; v++) {
                    acc[u][v] = __builtin_amdgcn_mfma_f32_16x16x32_f16(a_h[u], b_h[v], acc[u][v], 0, 0, 0);
                    acc[u][v] = __builtin_amdgcn_mfma_f32_16x16x32_f16(a_h[u], b_l[v], acc[u][v], 0, 0, 0);
                    acc[u][v] = __builtin_amdgcn_mfma_f32_16x16x32_f16(a_l[u], b_h[v], acc[u][v], 0, 0, 0);
                }
        }
        if (hasNext) {
            __syncthreads();
            *reinterpret_cast<half8*>(&Ah[lo0]) = nA0;
            *reinterpret_cast<half8*>(&Ah[lo1]) = nA1;
            *reinterpret_cast<half8*>(&Al[lo0]) = nAl0;
            *reinterpret_cast<half8*>(&Al[lo1]) = nAl1;
            *reinterpret_cast<half8*>(&Bh[lo0]) = nB0;
            *reinterpret_cast<half8*>(&Bh[lo1]) = nB1;
            *reinterpret_cast<half8*>(&Bl[lo0]) = nBl0;
            *reinterpret_cast<half8*>(&Bl[lo1]) = nBl1;
            __syncthreads();
        }
    }
    // normal write: C/D layout col=lane&15, row=(lane>>4)*4+reg (m89-verified)
#pragma unroll
    for (int u = 0; u < 2; u++) {
        int r = I + wr * 32 + u * 16 + q * 4;
#pragma unroll
        for (int v = 0; v < 2; v++) {
            int c = J + wc * 32 + v * 16 + lr;
#pragma unroll
            for (int i2 = 0; i2 < 4; i2++)
                fit[(size_t)(r + i2) * NN + c] = acc[u][v][i2];
        }
    }
    // mirror write (exact transpose) via per-wave padded LDS transpose [16][33]
    if (bi != bj) {
        __syncthreads();                         // all waves done with staging LDS
        float* Tw = reinterpret_cast<float*>(SM) + wid * 528;   // 16*33 floats/wave
#pragma unroll
        for (int v = 0; v < 2; v++) {
#pragma unroll
            for (int u = 0; u < 2; u++)
#pragma unroll
                for (int i2 = 0; i2 < 4; i2++)
                    Tw[lr * 33 + u * 16 + q * 4 + i2] = acc[u][v][i2];
            // wave-internal LDS RAW: compiler inserts lgkmcnt before dependent store
            int cbase = J + wc * 32 + v * 16;
            int rbase = I + wr * 32;
#pragma unroll
            for (int rr = 0; rr < 8; rr++) {
                int row = rr * 2 + (lane >> 5);
                int col = lane & 31;
                fit[(size_t)(cbase + row) * NN + rbase + col] = Tw[row * 33 + col];
            }
        }
    }
}

// ---------- A1 bitset: edge && !diag && fitness>=0 ----------
__global__ void k_bits(const u64* __restrict__ EBw, const float* __restrict__ fit,
                       u64* __restrict__ A1w) {
    int i = blockIdx.x;
    int t = threadIdx.x;
    int lane = t & 63, wv = t >> 6;
    for (int q = 0; q < 8; q++) {
        int j = q * 256 + t;
        u64 eb = EBw[(size_t)i * NW + (j >> 6)];
        float f = fit[(size_t)i * NN + j];
        bool pred = ((eb >> (j & 63)) & 1) && (j != i) && (f >= 0.f);
        u64 word = __ballot(pred);
        if (lane == 0) A1w[i * NW + q * 4 + wv] = word;
    }
}

// ---------- fused: boolean A1@A1 (A2/CL) + cluster scores ----------
__global__ __launch_bounds__(256) void k_paths2s(const u64* __restrict__ A1w,
                                                 const float* __restrict__ fit,
                                                 u64* __restrict__ A2w, u64* __restrict__ CLw,
                                                 float* cs) {
    int i = blockIdx.x;
    __shared__ u64 rowA[NW];
    __shared__ u64 rowA2[NW];
    __shared__ u64 part[8][NW];
    int t = threadIdx.x;
    if (t < NW) rowA[t] = A1w[i * NW + t];
    __syncthreads();
    int g = t >> 5, w = t & 31;
    u64 acc = 0;
    for (int ww = 0; ww < 4; ww++) {
        u64 bits = rowA[g * 4 + ww];
        int kbase = (g * 4 + ww) * 64;
        while (bits) {
            int k = __ffsll((unsigned long long)bits) - 1;
            bits &= bits - 1;
            acc |= A1w[(size_t)(kbase + k) * NW + w];
        }
    }
    part[g][w] = acc;
    __syncthreads();
    if (g == 0) {
        u64 p2 = part[0][w];
#pragma unroll
        for (int gg = 1; gg < 8; gg++) p2 |= part[gg][w];
        if ((i >> 6) == w) p2 &= ~(1ull << (i & 63));   // zero diagonal of A1@A1
        u64 a1 = rowA[w];
        u64 a2 = p2 & ~a1;
        u64 cl = a1 | a2;
        A2w[i * NW + w] = a2;
        CLw[i * NW + w] = cl;
        rowA2[w] = a2;
    }
    __syncthreads();
    float s1 = 0.f, s2 = 0.f;
    int d1 = 0, d2 = 0;
    for (int q = 0; q < 8; q++) {
        int j = q * 256 + t;
        float f = fit[(size_t)i * NN + j];
        int ww = j >> 6, b = j & 63;
        u64 a1 = rowA[ww], a2 = rowA2[ww];
        if ((a1 >> b) & 1) { s1 += f; d1++; }
        if ((a2 >> b) & 1) { s2 += f; d2++; }
    }
    for (int off = 32; off; off >>= 1) {
        s1 += __shfl_down(s1, off);
        s2 += __shfl_down(s2, off);
        d1 += __shfl_down(d1, off);
        d2 += __shfl_down(d2, off);
    }
    __shared__ float rs1[4], rs2[4];
    __shared__ int rd1[4], rd2[4];
    int wid = t >> 6, lane = t & 63;
    if (lane == 0) { rs1[wid] = s1; rs2[wid] = s2; rd1[wid] = d1; rd2[wid] = d2; }
    __syncthreads();
    if (t == 0) {
        float S1 = 0.f, S2 = 0.f; int D1 = 0, D2 = 0;
        for (int w2 = 0; w2 < 4; w2++) { S1 += rs1[w2]; S2 += rs2[w2]; D1 += rd1[w2]; D2 += rd2[w2]; }
        float v1 = D1 > 0 ? S1 / (float)D1 : 0.f;
        float v2 = D2 > 0 ? S2 / (float)D2 : 0.f;
        cs[i] = 0.5f * (v1 + v2);
    }
}

// ---------- fused: local extrema + colAny reduction ----------
__global__ __launch_bounds__(256) void k_extcol(const u64* __restrict__ A1w,
                                                const u64* __restrict__ CLw,
                                                const float* __restrict__ cs,
                                                unsigned char* is_c, u64* centerBits,
                                                u64* colAny) {
    int i = blockIdx.x, t = threadIdx.x;
    __shared__ u64 part[8][NW];
    if (i < 64) {
        int sub = t >> 5, w = t & 31;
        u64 acc = 0;
#pragma unroll
        for (int k = 0; k < 4; k++) {
            int r = i * 32 + sub + k * 8;
            acc |= CLw[(size_t)r * NW + w];
        }
        part[sub][w] = acc;
    }
    float ci = cs[i];
    int ok = 1;
    for (int q = 0; q < 8; q++) {
        int j = q * 256 + t;
        u64 a1 = A1w[i * NW + (j >> 6)];
        float other = ((a1 >> (j & 63)) & 1) ? cs[j] : 0.0f;
        ok &= ((ci - other) > 0.0f) ? 1 : 0;
    }
    int all = __syncthreads_and(ok);
    if (t == 0) {
        is_c[i] = (unsigned char)(all ? 1 : 0);
        if (all) atomicOr(&centerBits[i >> 6], 1ull << (i & 63));
    }
    if (i < 64 && t < NW) {
        u64 v = part[0][t];
#pragma unroll
        for (int s = 1; s < 8; s++) v |= part[s][t];
        atomicOr(&colAny[t], v);
    }
}

// ---------- pooled: sparse-column M^T @ emb, 16-deep prefetch gather ----------
__global__ __launch_bounds__(256) void k_pooled(const float* __restrict__ fit,
                                                const float* __restrict__ emb,
                                                const u64* __restrict__ CLw,
                                                const u64* __restrict__ centerBits,
                                                const u64* __restrict__ colAny,
                                                const unsigned char* __restrict__ is_c,
                                                float* __restrict__ out) {
    int j = blockIdx.x;
    int t = threadIdx.x;
    bool red = ((colAny[j >> 6] >> (j & 63)) & 1ull) == 0ull;
    for (int w = 0; w < NW; w++) red |= (CLw[(size_t)j * NW + w] & centerBits[w]) != 0ull;
    const float2* embj = reinterpret_cast<const float2*>(emb + (size_t)j * DD);
    float2* outj = reinterpret_cast<float2*>(out + (size_t)j * DD);
    bool active = is_c[j] && !red;
    if (!active) {
        float dg = red ? 0.0f : 1.0f;
        float2 v = embj[t];
        float2 o; o.x = v.x * dg; o.y = v.y * dg;
        outj[t] = o;
        return;
    }
    __shared__ int lidx[NN];
    __shared__ float lwt[NN];
    __shared__ int wcnt[4];
    int wid = t >> 6, lane = t & 63;
    int wsh = j >> 6;
    u64 bmask = 1ull << (j & 63);
    int total = 0;
    for (int qq = 0; qq < 8; qq++) {
        int i = qq * 256 + t;
        u64 cw = CLw[(size_t)i * NW + wsh];
        bool p = (cw & bmask) != 0ull;
        float f = 0.f;
        if (p) f = fit[(size_t)i * NN + j];
        u64 mask = __ballot(p);
        if (lane == 0) wcnt[wid] = __popcll(mask);
        __syncthreads();
        int off = total;
        for (int w = 0; w < wid; w++) off += wcnt[w];
        int tq = wcnt[0] + wcnt[1] + wcnt[2] + wcnt[3];
        if (p) {
            int pos = off + __popcll(mask & ((1ull << lane) - 1ull));
            lidx[pos] = i;
            lwt[pos] = f;
        }
        total += tq;
        __syncthreads();
    }
    float2 acc = {0.f, 0.f};
    int k = 0;
    for (; k + 16 <= total; k += 16) {
        int idxr[16];
        float wtr[16];
#pragma unroll
        for (int u = 0; u < 16; u++) { idxr[u] = lidx[k + u]; wtr[u] = lwt[k + u]; }
        float2 e[16];
#pragma unroll
        for (int u = 0; u < 16; u++)
            e[u] = reinterpret_cast<const float2*>(emb + (size_t)idxr[u] * DD)[t];
#pragma unroll
        for (int u = 0; u < 16; u++) {
            acc.x += wtr[u] * e[u].x;
            acc.y += wtr[u] * e[u].y;
        }
    }
    for (; k < total; k++) {
        int i = lidx[k];
        float w = lwt[k];
        float2 e = reinterpret_cast<const float2*>(emb + (size_t)i * DD)[t];
        acc.x += w * e.x;
        acc.y += w * e.y;
    }
    float2 v = embj[t];
    acc.x += v.x;
    acc.y += v.y;
    outj[t] = acc;
}

// ---------- launch ----------
extern "C" void kernel_launch(void* const* d_in, const int* in_sizes, int n_in,
                              void* d_out, int out_size, void* d_ws, size_t ws_size,
                              hipStream_t stream) {
    const float* emb = (const float*)d_in[0];
    const int*   ei  = (const int*)d_in[1];
    // d_in[2] = edge_matrix  (reconstructed from edge_index as a bitset)
    // d_in[3] = edge_matrix_weight (unused by reference math)
    const float* Wsc = (const float*)d_in[4];
    const float* bsc = (const float*)d_in[5];
    float* out = (float*)d_out;

    char* ws = (char*)d_ws;
    size_t off = 0;
    auto alloc = [&](size_t bytes) -> char* {
        char* p = ws + off;
        off = (off + bytes + 255) & ~(size_t)255;
        return p;
    };
    float* fit  = (float*)alloc((size_t)NN * NN * 4);      // 16 MB
    // zh/zl (4 MB) die after k_fitness; A1w/A2w/CLw born after -> alias
    char*  zblk = alloc((size_t)2 * NN * DD * 2);          // 4 MB shared region
    _Float16* zh = (_Float16*)zblk;
    _Float16* zl = (_Float16*)(zblk + (size_t)NN * DD * 2);
    u64* A1w = (u64*)zblk;
    u64* A2w = (u64*)(zblk + (size_t)NN * NW * 8);
    u64* CLw = (u64*)(zblk + (size_t)2 * NN * NW * 8);
    u64*   EBw        = (u64*)alloc((size_t)NN * NW * 8);  // live across fitness
    u64*   centerBits = (u64*)alloc(NW * 8);
    u64*   colAny     = (u64*)alloc(NW * 8);
    float* inv_norm   = (float*)alloc(NN * 4);
    float* av         = (float*)alloc(NN * 4);
    float* cv         = (float*)alloc(NN * 4);
    float* ssum       = (float*)alloc(NN * 4);
    float* cs         = (float*)alloc(NN * 4);
    unsigned char* is_c = (unsigned char*)alloc(NN);

    k_node<<<dim3(NN), dim3(256), 0, stream>>>(emb, Wsc, inv_norm, av, cv, zh, zl,
                                               ssum, centerBits, colAny, EBw);
    k_edgeA<<<dim3(EE / 256), dim3(256), 0, stream>>>(ei, av, cv, bsc, ssum, EBw);
    k_fitness<<<dim3(528), dim3(256), 0, stream>>>(zh, zl, fit);
    k_edge_scatter<<<dim3(EE / 256), dim3(256), 0, stream>>>(ei, av, cv, bsc, ssum, fit);
    k_bits<<<dim3(NN), dim3(256), 0, stream>>>(EBw, fit, A1w);
    k_paths2s<<<dim3(NN), dim3(256), 0, stream>>>(A1w, fit, A2w, CLw, cs);
    k_extcol<<<dim3(NN), dim3(256), 0, stream>>>(A1w, CLw, cs, is_c, centerBits, colAny);
    k_pooled<<<dim3(NN), dim3(256), 0, stream>>>(fit, emb, CLw, centerBits, colAny, is_c, out);
}